// Round 3
// baseline (267.842 us; speedup 1.0000x reference)
//
#include <hip/hip_runtime.h>
#include <hip/hip_bf16.h>

// Problem constants: B=2, N=2048, D=512, H=8, hd=64
typedef __bf16 bf16x8 __attribute__((ext_vector_type(8)));
typedef float f32x4 __attribute__((ext_vector_type(4)));
typedef unsigned short u16x8 __attribute__((ext_vector_type(8)));

#define LOG2E 1.44269504f

__device__ __forceinline__ unsigned short f2bu(float f) {
    __hip_bfloat16 h = __float2bfloat16(f);
    unsigned short u;
    __builtin_memcpy(&u, &h, 2);
    return u;
}

__device__ __forceinline__ float fexp2(float x) {
#if __has_builtin(__builtin_amdgcn_exp2f)
    return __builtin_amdgcn_exp2f(x);
#else
    return __expf(x * 0.69314718f);
#endif
}

__device__ __forceinline__ float bu2f(unsigned short u) {
    unsigned int v = ((unsigned int)u) << 16;
    float f;
    __builtin_memcpy(&f, &v, 4);
    return f;
}

// async global->LDS, 16B per lane. LDS base must be wave-uniform; HW appends lane*16.
#define GLDS16(gp, lp) __builtin_amdgcn_global_load_lds( \
    (const __attribute__((address_space(1))) unsigned int*)(gp), \
    (__attribute__((address_space(3))) unsigned int*)(lp), 16, 0, 0)

// ---- workspace layout (bytes). mperm overlays xb/wt/Vb (dead by the time k_adjp runs).
#define OFF_QS  0u                          // Q*(0.125*log2e) bf16  4 MB
#define OFF_KB  4194304u                    // K bf16                4 MB
#define OFF_VT  8388608u                    // V^T [b,h,d,n] bf16    4 MB
#define OFF_CV  12582912u                   // cv2[b,n] f32 = 2^((c-8)*log2e)  16 KB
#define OFF_MP  12648448u                   // m permuted bf16       16 MB  (to 29.4 MB)
#define OFF_XB  OFF_MP                      // x bf16 (transient)    4 MB
#define OFF_WT  (OFF_MP + 4194304u)         // W^T bf16 (transient)  1.5 MB
#define OFF_VB  (OFF_MP + 5767168u)         // V bf16 (transient)    4 MB

// ---------------- prep: x->bf16 AND cv2[row] = 2^((x@wg[D:] - 8)*log2e) ----------------
__global__ void k_prep(const float* __restrict__ x, const float* __restrict__ wg,
                       unsigned short* __restrict__ xb, float* __restrict__ cv2) {
    int row = blockIdx.x * 4 + (threadIdx.x >> 6);   // 4096 rows
    int l = threadIdx.x & 63;
    const float4* xr = reinterpret_cast<const float4*>(x + (size_t)row * 512);
    float4 a = xr[l * 2], b2 = xr[l * 2 + 1];
    ushort4 o0, o1;
    o0.x = f2bu(a.x);  o0.y = f2bu(a.y);  o0.z = f2bu(a.z);  o0.w = f2bu(a.w);
    o1.x = f2bu(b2.x); o1.y = f2bu(b2.y); o1.z = f2bu(b2.z); o1.w = f2bu(b2.w);
    ushort4* dst = reinterpret_cast<ushort4*>(xb + (size_t)row * 512);
    dst[l * 2] = o0; dst[l * 2 + 1] = o1;
    const float4* wr = reinterpret_cast<const float4*>(wg + 512);
    float4 g0 = wr[l * 2], g1 = wr[l * 2 + 1];
    float s = a.x * g0.x + a.y * g0.y + a.z * g0.z + a.w * g0.w
            + b2.x * g1.x + b2.y * g1.y + b2.z * g1.z + b2.w * g1.w;
#pragma unroll
    for (int off = 32; off >= 1; off >>= 1) s += __shfl_xor(s, off, 64);
    if (l == 0) cv2[row] = fexp2((s - 8.0f) * LOG2E);
}

// ---------------- prep: Wt[n][k] = bf16(W[k][n]) for q,k,v ----------------
__global__ void k_wt(const float* __restrict__ w0, const float* __restrict__ w1,
                     const float* __restrict__ w2, unsigned short* __restrict__ wt) {
    int z = blockIdx.x;
    int k0 = (blockIdx.y >> 3) * 64, n0 = (blockIdx.y & 7) * 64;
    const float* W = (z == 0) ? w0 : ((z == 1) ? w1 : w2);
    __shared__ float T[64][65];
    int c = threadIdx.x & 63, r0 = threadIdx.x >> 6;
#pragma unroll
    for (int i = 0; i < 16; i++) { int r = r0 + i * 4; T[r][c] = W[(k0 + r) * 512 + n0 + c]; }
    __syncthreads();
    unsigned short* Wt = wt + z * (512 * 512);
#pragma unroll
    for (int i = 0; i < 16; i++) { int a = r0 + i * 4; Wt[(n0 + a) * 512 + k0 + c] = f2bu(T[c][a]); }
}

// ---------------- prep: mperm = bf16((adj+eps)*cv2[j]) in MFMA-lane order ----------------
// mperm[((b*128+ic)*32+jt)*1024 + l*16 + r*4 + nt] = (adj[b][ic*16+q*4+r][jt*64+nt*16+cl]+eps)*cv2[b,j]
// where l = q*16+cl. In k_attn each lane reads its 16 factors as two 16-B loads.
__global__ void k_adjp(const float* __restrict__ adj, const float* __restrict__ cv2,
                       unsigned short* __restrict__ mp) {
    int bic = blockIdx.x;              // b*128 + ic
    int b = bic >> 7, ic = bic & 127;
    int tid = threadIdx.x;
    int r = tid >> 6, l = tid & 63, q = l >> 4, cl = l & 15;
    const float* arow = adj + ((size_t)(b * 2048 + ic * 16 + q * 4 + r)) * 2048;
    const float* cvb = cv2 + b * 2048;
    unsigned short* outb = mp + (size_t)bic * 32 * 1024;
    for (int jt = 0; jt < 32; jt++) {
        ushort4 o;
        unsigned short* op = (unsigned short*)&o;
#pragma unroll
        for (int nt = 0; nt < 4; nt++) {
            int j = jt * 64 + nt * 16 + cl;
            op[nt] = f2bu((arow[j] + 1e-9f) * cvb[j]);
        }
        *reinterpret_cast<ushort4*>(outb + jt * 1024 + l * 16 + r * 4) = o;
    }
}

// ---------------- fused QKV projection GEMM (128x128 tile, bf16 MFMA) ----------------
__global__ __launch_bounds__(256) void k_gemm(
    const unsigned short* __restrict__ xb, const unsigned short* __restrict__ wt,
    const float* __restrict__ bq, const float* __restrict__ bk, const float* __restrict__ bv,
    unsigned short* __restrict__ Qs, unsigned short* __restrict__ Kb,
    unsigned short* __restrict__ Vb) {
    __shared__ __align__(16) unsigned short As[128 * 32];
    __shared__ __align__(16) unsigned short Bs[128 * 32];
    int z = blockIdx.z;
    const unsigned short* Wt = wt + z * (512 * 512);
    const float* bias = (z == 0) ? bq : ((z == 1) ? bk : bv);
    unsigned short* Cout = (z == 0) ? Qs : ((z == 1) ? Kb : Vb);
    float scale = (z == 0) ? (0.125f * LOG2E) : 1.0f;   // Q pre-scaled by log2e/sqrt(64)
    int m0 = blockIdx.x * 128, n0 = blockIdx.y * 128;
    int tid = threadIdx.x, w = tid >> 6, l = tid & 63;
    int q = l >> 4, cl = l & 15;
    f32x4 acc[4][4];
#pragma unroll
    for (int mt = 0; mt < 4; mt++)
#pragma unroll
        for (int nt = 0; nt < 4; nt++)
#pragma unroll
            for (int r = 0; r < 4; r++) acc[mt][nt][r] = 0.f;

    int arow = w * 32 + (l >> 2);
    int achunk = (l & 3) * 8;
    for (int k0 = 0; k0 < 512; k0 += 32) {
#pragma unroll
        for (int e = 0; e < 2; e++) {
            GLDS16(xb + (m0 + arow + e * 16) * 512 + k0 + achunk, As + w * 1024 + e * 512);
            GLDS16(Wt + (n0 + arow + e * 16) * 512 + k0 + achunk, Bs + w * 1024 + e * 512);
        }
        __syncthreads();
        bf16x8 af[4], bfr[4];
#pragma unroll
        for (int mt = 0; mt < 4; mt++)
            af[mt] = *reinterpret_cast<const bf16x8*>(As + (64 * (w >> 1) + 16 * mt + cl) * 32 + q * 8);
#pragma unroll
        for (int nt = 0; nt < 4; nt++)
            bfr[nt] = *reinterpret_cast<const bf16x8*>(Bs + (64 * (w & 1) + 16 * nt + cl) * 32 + q * 8);
#pragma unroll
        for (int mt = 0; mt < 4; mt++)
#pragma unroll
            for (int nt = 0; nt < 4; nt++)
                acc[mt][nt] = __builtin_amdgcn_mfma_f32_16x16x32_bf16(af[mt], bfr[nt], acc[mt][nt], 0, 0, 0);
        __syncthreads();
    }
#pragma unroll
    for (int nt = 0; nt < 4; nt++) {
        int col = n0 + 64 * (w & 1) + 16 * nt + cl;
        float bv_ = bias[col];
#pragma unroll
        for (int mt = 0; mt < 4; mt++) {
#pragma unroll
            for (int r = 0; r < 4; r++) {
                int row = m0 + 64 * (w >> 1) + 16 * mt + 4 * q + r;
                Cout[row * 512 + col] = f2bu((acc[mt][nt][r] + bv_) * scale);
            }
        }
    }
}

// ---------------- V -> V^T  ([b,h,d,n] so PV B-fragments are contiguous) ----------------
__global__ void k_vt(const unsigned short* __restrict__ Vb, unsigned short* __restrict__ Vt) {
    int s = blockIdx.y;            // s = b*8 + h
    int b = s >> 3, h = s & 7;
    int n0 = blockIdx.x * 64;
    __shared__ unsigned short T[64][66];
    int c = threadIdx.x & 63, r0 = threadIdx.x >> 6;
#pragma unroll
    for (int i = 0; i < 16; i++) {
        int r = r0 + i * 4;
        T[r][c] = Vb[(b * 2048 + n0 + r) * 512 + h * 64 + c];
    }
    __syncthreads();
#pragma unroll
    for (int i = 0; i < 16; i++) {
        int a = r0 + i * 4;
        Vt[(s * 64 + a) * 2048 + n0 + c] = T[c][a];
    }
}

// ---------------- flash attention, fixed-max, precomputed multiplier ----------------
// 512 blocks x 512 threads (8 waves). Block = (b, it64, h). Wave w: rh=w>>2 (32-row half),
// jq=w&3 (512-col quarter, 8 j-tiles of 64). No barrier in loop; p = exp2(S)*m.
// Cross-jq combine via ds_add_f32 into flat ACC, then jq==0 waves normalize+store.
__global__ __launch_bounds__(512) void k_attn(
    const unsigned short* __restrict__ Qs, const unsigned short* __restrict__ Kb,
    const unsigned short* __restrict__ Vt, const unsigned short* __restrict__ mp,
    const float* __restrict__ x, float* __restrict__ out) {
    __shared__ __align__(16) unsigned short P[8][32 * 72];  // per-wave P tile, 36864 B
    __shared__ float ACC[6144];  // O: [rh][rc][nt][r][l] 4096 floats, L: +4096 [rh][rc][r][l] 2048
    int bid = blockIdx.x;
    int h = bid >> 6, s = bid & 63, b = s >> 5, it = s & 31;
    int i0 = it * 64;
    int tid = threadIdx.x, w = tid >> 6, l = tid & 63, q = l >> 4, cl = l & 15;
    int rh = w >> 2, jq = w & 3;
    int rowbase = i0 + rh * 32;

#pragma unroll
    for (int k = 0; k < 12; k++) ACC[tid + k * 512] = 0.f;
    __syncthreads();

    // Q fragments (A-layout: m=cl, k=q*8+j), pre-scaled by log2e/8
    bf16x8 qf[2][2];
#pragma unroll
    for (int rc = 0; rc < 2; rc++) {
        const unsigned short* qp = Qs + (size_t)(b * 2048 + rowbase + rc * 16 + cl) * 512 + h * 64 + q * 8;
        qf[rc][0] = *reinterpret_cast<const bf16x8*>(qp);
        qf[rc][1] = *reinterpret_cast<const bf16x8*>(qp + 32);
    }
    f32x4 O[2][4];
    float lsum[2][4];
#pragma unroll
    for (int rc = 0; rc < 2; rc++) {
#pragma unroll
        for (int nt = 0; nt < 4; nt++)
#pragma unroll
            for (int r = 0; r < 4; r++) O[rc][nt][r] = 0.f;
#pragma unroll
        for (int r = 0; r < 4; r++) lsum[rc][r] = 0.f;
    }

    const unsigned short* Kh = Kb + (size_t)b * 2048 * 512 + h * 64;
    const unsigned short* Vh = Vt + ((size_t)(b * 8 + h) * 64) * 2048;
    // mperm base for this wave's two 16-row chunks: ic = it*4 + rh*2 + rc
    const unsigned short* mb0 = mp + ((size_t)((b * 128 + it * 4 + rh * 2 + 0) * 32) ) * 1024 + l * 16;
    const unsigned short* mb1 = mp + ((size_t)((b * 128 + it * 4 + rh * 2 + 1) * 32) ) * 1024 + l * 16;
    unsigned short* pw = &P[w][0];
    int jbase0 = jq * 512;

#pragma unroll 2
    for (int t = 0; t < 8; t++) {
        int jb = jbase0 + t * 64;
        int jt = jq * 8 + t;
        // multiplier fragments (16 bf16/lane/rc, contiguous)
        u16x8 mh[2][2];
        mh[0][0] = *reinterpret_cast<const u16x8*>(mb0 + (size_t)jt * 1024);
        mh[0][1] = *reinterpret_cast<const u16x8*>(mb0 + (size_t)jt * 1024 + 8);
        mh[1][0] = *reinterpret_cast<const u16x8*>(mb1 + (size_t)jt * 1024);
        mh[1][1] = *reinterpret_cast<const u16x8*>(mb1 + (size_t)jt * 1024 + 8);
        // K fragments
        bf16x8 kf[4][2];
#pragma unroll
        for (int nt = 0; nt < 4; nt++) {
            const unsigned short* kp = Kh + (size_t)(jb + 16 * nt + cl) * 512 + q * 8;
            kf[nt][0] = *reinterpret_cast<const bf16x8*>(kp);
            kf[nt][1] = *reinterpret_cast<const bf16x8*>(kp + 32);
        }
        // V fragments (used at iter end; issue early)
        bf16x8 vf[4][2];
#pragma unroll
        for (int nt = 0; nt < 4; nt++) {
            const unsigned short* vp = Vh + (size_t)(16 * nt + cl) * 2048 + jb + q * 8;
            vf[nt][0] = *reinterpret_cast<const bf16x8*>(vp);
            vf[nt][1] = *reinterpret_cast<const bf16x8*>(vp + 32);
        }
        // S = (Q*log2e/8) K^T
        f32x4 S[2][4];
#pragma unroll
        for (int rc = 0; rc < 2; rc++)
#pragma unroll
            for (int nt = 0; nt < 4; nt++) {
#pragma unroll
                for (int r = 0; r < 4; r++) S[rc][nt][r] = 0.f;
                S[rc][nt] = __builtin_amdgcn_mfma_f32_16x16x32_bf16(qf[rc][0], kf[nt][0], S[rc][nt], 0, 0, 0);
                S[rc][nt] = __builtin_amdgcn_mfma_f32_16x16x32_bf16(qf[rc][1], kf[nt][1], S[rc][nt], 0, 0, 0);
            }
        // p = exp2(S) * m; accumulate per-lane row sums; stash p into S
#pragma unroll
        for (int rc = 0; rc < 2; rc++)
#pragma unroll
            for (int r = 0; r < 4; r++)
#pragma unroll
                for (int nt = 0; nt < 4; nt++) {
                    float mv = bu2f(mh[rc][r >> 1][(r & 1) * 4 + nt]);
                    float p = fexp2(S[rc][nt][r]) * mv;
                    S[rc][nt][r] = p;
                    lsum[rc][r] += p;
                }
        // P: C/D layout -> A layout via per-wave LDS (wave-local; no barrier needed)
#pragma unroll
        for (int rc = 0; rc < 2; rc++)
#pragma unroll
            for (int nt = 0; nt < 4; nt++)
#pragma unroll
                for (int r = 0; r < 4; r++)
                    pw[(rc * 16 + q * 4 + r) * 72 + 16 * nt + cl] = f2bu(S[rc][nt][r]);
        // O += P V
#pragma unroll
        for (int rc = 0; rc < 2; rc++) {
            bf16x8 pf0 = *reinterpret_cast<const bf16x8*>(pw + rc * 1152 + cl * 72 + q * 8);
            bf16x8 pf1 = *reinterpret_cast<const bf16x8*>(pw + rc * 1152 + cl * 72 + 32 + q * 8);
#pragma unroll
            for (int nt = 0; nt < 4; nt++) {
                O[rc][nt] = __builtin_amdgcn_mfma_f32_16x16x32_bf16(pf0, vf[nt][0], O[rc][nt], 0, 0, 0);
                O[rc][nt] = __builtin_amdgcn_mfma_f32_16x16x32_bf16(pf1, vf[nt][1], O[rc][nt], 0, 0, 0);
            }
        }
    }

    // combine j-quarters via LDS float atomics (fixed-M: plain sums)
#pragma unroll
    for (int rc = 0; rc < 2; rc++) {
#pragma unroll
        for (int nt = 0; nt < 4; nt++)
#pragma unroll
            for (int r = 0; r < 4; r++)
                atomicAdd(&ACC[((((rh * 2 + rc) * 4 + nt) * 4 + r) * 64) + l], O[rc][nt][r]);
#pragma unroll
        for (int r = 0; r < 4; r++)
            atomicAdd(&ACC[4096 + (((rh * 2 + rc) * 4 + r) * 64) + l], lsum[rc][r]);
    }
    __syncthreads();
    if (jq == 0) {
#pragma unroll
        for (int rc = 0; rc < 2; rc++) {
            float inv[4];
#pragma unroll
            for (int r = 0; r < 4; r++) {
                float t = ACC[4096 + (((rh * 2 + rc) * 4 + r) * 64) + l];
#pragma unroll
                for (int m = 8; m >= 1; m >>= 1) t += __shfl_xor(t, m, 64);
                inv[r] = 1.0f / t;
            }
#pragma unroll
            for (int nt = 0; nt < 4; nt++)
#pragma unroll
                for (int r = 0; r < 4; r++) {
                    float o = ACC[((((rh * 2 + rc) * 4 + nt) * 4 + r) * 64) + l];
                    int row = b * 2048 + rowbase + rc * 16 + q * 4 + r;
                    int idx = row * 512 + h * 64 + 16 * nt + cl;
                    out[idx] = o * inv[r] + x[idx];
                }
        }
    }
}

extern "C" void kernel_launch(void* const* d_in, const int* in_sizes, int n_in,
                              void* d_out, int out_size, void* d_ws, size_t ws_size,
                              hipStream_t stream) {
    const float* x   = (const float*)d_in[0];
    const float* adj = (const float*)d_in[1];
    const float* Wq  = (const float*)d_in[2];
    const float* bq  = (const float*)d_in[3];
    const float* Wk  = (const float*)d_in[4];
    const float* bk  = (const float*)d_in[5];
    const float* Wv  = (const float*)d_in[6];
    const float* bv  = (const float*)d_in[7];
    const float* wg  = (const float*)d_in[8];
    // d_in[9] (b_g) unused: row-constant bias cancels in softmax
    float* out = (float*)d_out;
    char* ws = (char*)d_ws;
    unsigned short* Qs = (unsigned short*)(ws + OFF_QS);
    unsigned short* Kb = (unsigned short*)(ws + OFF_KB);
    unsigned short* Vt = (unsigned short*)(ws + OFF_VT);
    float* cv2 = (float*)(ws + OFF_CV);
    unsigned short* mpm = (unsigned short*)(ws + OFF_MP);
    unsigned short* xb = (unsigned short*)(ws + OFF_XB);
    unsigned short* wt = (unsigned short*)(ws + OFF_WT);
    unsigned short* Vb = (unsigned short*)(ws + OFF_VB);

    k_prep<<<1024, 256, 0, stream>>>(x, wg, xb, cv2);
    k_wt<<<dim3(3, 64), 256, 0, stream>>>(Wq, Wk, Wv, wt);
    k_gemm<<<dim3(32, 4, 3), 256, 0, stream>>>(xb, wt, bq, bk, bv, Qs, Kb, Vb);
    k_vt<<<dim3(32, 16), 256, 0, stream>>>(Vb, Vt);
    k_adjp<<<256, 256, 0, stream>>>(adj, cv2, mpm);   // clobbers xb/wt/Vb (dead)
    k_attn<<<512, 512, 0, stream>>>(Qs, Kb, Vt, mpm, x, out);
}

// Round 4
// 244.674 us; speedup vs baseline: 1.0947x; 1.0947x over previous
//
#include <hip/hip_runtime.h>
#include <hip/hip_bf16.h>

// Problem constants: B=2, N=2048, D=512, H=8, hd=64
typedef __bf16 bf16x8 __attribute__((ext_vector_type(8)));
typedef float f32x4 __attribute__((ext_vector_type(4)));
typedef unsigned short u16x8 __attribute__((ext_vector_type(8)));

#define LOG2E 1.44269504f

__device__ __forceinline__ unsigned short f2bu(float f) {
    __hip_bfloat16 h = __float2bfloat16(f);
    unsigned short u;
    __builtin_memcpy(&u, &h, 2);
    return u;
}

__device__ __forceinline__ float fexp2(float x) {
#if __has_builtin(__builtin_amdgcn_exp2f)
    return __builtin_amdgcn_exp2f(x);
#else
    return __expf(x * 0.69314718f);
#endif
}

__device__ __forceinline__ float bu2f(unsigned short u) {
    unsigned int v = ((unsigned int)u) << 16;
    float f;
    __builtin_memcpy(&f, &v, 4);
    return f;
}

// async global->LDS, 16B per lane. LDS base must be wave-uniform; HW appends lane*16.
#define GLDS16(gp, lp) __builtin_amdgcn_global_load_lds( \
    (const __attribute__((address_space(1))) unsigned int*)(gp), \
    (__attribute__((address_space(3))) unsigned int*)(lp), 16, 0, 0)

// ---- workspace layout (bytes). xb/wt/Vb are transient, overlaid on mperm region.
#define OFF_QS  0u                          // Q*(0.125*log2e) bf16  4 MB
#define OFF_KB  4194304u                    // K bf16                4 MB
#define OFF_VT  8388608u                    // V^T [b,h,d,n] bf16    4 MB
#define OFF_CV  12582912u                   // cv2[b,n] f32 = 2^((c-8)*log2e)  16 KB
#define OFF_MP  12648448u                   // m permuted bf16       16.78 MB (ends 29425664)
#define OFF_PO  29425664u                   // partial O bf16, 1024 slabs x 4096  8.39 MB
#define OFF_PL  37814272u                   // partial lsum f32, 1024 slabs x 64  256 KB
#define OFF_XB  OFF_MP                      // x bf16 (transient)    4 MB
#define OFF_WT  (OFF_MP + 4194304u)         // W^T bf16 (transient)  1.5 MB
#define OFF_VB  (OFF_MP + 5767168u)         // V bf16 (transient)    4 MB

// ---------------- prep: x->bf16 AND cv2[row] = 2^((x@wg[D:] - 8)*log2e) ----------------
__global__ void k_prep(const float* __restrict__ x, const float* __restrict__ wg,
                       unsigned short* __restrict__ xb, float* __restrict__ cv2) {
    int row = blockIdx.x * 4 + (threadIdx.x >> 6);   // 4096 rows
    int l = threadIdx.x & 63;
    const float4* xr = reinterpret_cast<const float4*>(x + (size_t)row * 512);
    float4 a = xr[l * 2], b2 = xr[l * 2 + 1];
    ushort4 o0, o1;
    o0.x = f2bu(a.x);  o0.y = f2bu(a.y);  o0.z = f2bu(a.z);  o0.w = f2bu(a.w);
    o1.x = f2bu(b2.x); o1.y = f2bu(b2.y); o1.z = f2bu(b2.z); o1.w = f2bu(b2.w);
    ushort4* dst = reinterpret_cast<ushort4*>(xb + (size_t)row * 512);
    dst[l * 2] = o0; dst[l * 2 + 1] = o1;
    const float4* wr = reinterpret_cast<const float4*>(wg + 512);
    float4 g0 = wr[l * 2], g1 = wr[l * 2 + 1];
    float s = a.x * g0.x + a.y * g0.y + a.z * g0.z + a.w * g0.w
            + b2.x * g1.x + b2.y * g1.y + b2.z * g1.z + b2.w * g1.w;
#pragma unroll
    for (int off = 32; off >= 1; off >>= 1) s += __shfl_xor(s, off, 64);
    if (l == 0) cv2[row] = fexp2((s - 8.0f) * LOG2E);
}

// ---------------- prep: Wt[n][k] = bf16(W[k][n]) for q,k,v ----------------
__global__ void k_wt(const float* __restrict__ w0, const float* __restrict__ w1,
                     const float* __restrict__ w2, unsigned short* __restrict__ wt) {
    int z = blockIdx.x;
    int k0 = (blockIdx.y >> 3) * 64, n0 = (blockIdx.y & 7) * 64;
    const float* W = (z == 0) ? w0 : ((z == 1) ? w1 : w2);
    __shared__ float T[64][65];
    int c = threadIdx.x & 63, r0 = threadIdx.x >> 6;
#pragma unroll
    for (int i = 0; i < 16; i++) { int r = r0 + i * 4; T[r][c] = W[(k0 + r) * 512 + n0 + c]; }
    __syncthreads();
    unsigned short* Wt = wt + z * (512 * 512);
#pragma unroll
    for (int i = 0; i < 16; i++) { int a = r0 + i * 4; Wt[(n0 + a) * 512 + k0 + c] = f2bu(T[c][a]); }
}

// ---------------- prep: mperm = bf16((adj+eps)*cv2[j]) in MFMA-lane order ----------------
// One thread per output ushort4; 8192 blocks, fully parallel, coalesced 8-B stores.
// mperm[bic*32768 + jt*1024 + l*16 + r*4 + nt] = m[b][ic*16+q*4+r][jt*64+nt*16+cl], l=q*16+cl
__global__ void k_adjp(const float* __restrict__ adj, const float* __restrict__ cv2,
                       unsigned short* __restrict__ mp) {
    int blk = blockIdx.x;              // bic*32 + jt
    int bic = blk >> 5, jt = blk & 31;
    int b = bic >> 7, ic = bic & 127;
    int t = threadIdx.x;               // 256: t = l*4 + r
    int l = t >> 2, r = t & 3, q = l >> 4, cl = l & 15;
    int row = ic * 16 + q * 4 + r;
    const float* ar = adj + ((size_t)(b * 2048 + row)) * 2048 + jt * 64;
    const float* cb = cv2 + b * 2048 + jt * 64;
    ushort4 o;
    o.x = f2bu((ar[cl]      + 1e-9f) * cb[cl]);
    o.y = f2bu((ar[16 + cl] + 1e-9f) * cb[16 + cl]);
    o.z = f2bu((ar[32 + cl] + 1e-9f) * cb[32 + cl]);
    o.w = f2bu((ar[48 + cl] + 1e-9f) * cb[48 + cl]);
    *reinterpret_cast<ushort4*>(mp + (size_t)bic * 32768 + jt * 1024 + t * 4) = o;
}

// ---------------- fused QKV projection GEMM (64x128 tiles -> 768 blocks = 3/CU) ----------------
__global__ __launch_bounds__(256) void k_gemm(
    const unsigned short* __restrict__ xb, const unsigned short* __restrict__ wt,
    const float* __restrict__ bq, const float* __restrict__ bk, const float* __restrict__ bv,
    unsigned short* __restrict__ Qs, unsigned short* __restrict__ Kb,
    unsigned short* __restrict__ Vb) {
    __shared__ __align__(16) unsigned short As[64 * 32];
    __shared__ __align__(16) unsigned short Bs[128 * 32];
    int z = blockIdx.z;
    const unsigned short* Wt = wt + z * (512 * 512);
    const float* bias = (z == 0) ? bq : ((z == 1) ? bk : bv);
    unsigned short* Cout = (z == 0) ? Qs : ((z == 1) ? Kb : Vb);
    float scale = (z == 0) ? (0.125f * LOG2E) : 1.0f;   // Q pre-scaled by log2e/sqrt(64)
    int m0 = blockIdx.x * 64, n0 = blockIdx.y * 128;
    int tid = threadIdx.x, w = tid >> 6, l = tid & 63;
    int q = l >> 4, cl = l & 15;
    f32x4 acc[8];
#pragma unroll
    for (int nt = 0; nt < 8; nt++)
#pragma unroll
        for (int r = 0; r < 4; r++) acc[nt][r] = 0.f;

    int arow = l >> 2, ach = (l & 3) * 8;
    for (int k0 = 0; k0 < 512; k0 += 32) {
        // wave w stages A rows [w*16,+16) and B rows [w*32,+32)
        GLDS16(xb + (size_t)(m0 + w * 16 + arow) * 512 + k0 + ach, As + w * 512);
#pragma unroll
        for (int e = 0; e < 2; e++)
            GLDS16(Wt + (size_t)(n0 + w * 32 + e * 16 + arow) * 512 + k0 + ach, Bs + w * 1024 + e * 512);
        __syncthreads();
        bf16x8 af = *reinterpret_cast<const bf16x8*>(As + (w * 16 + cl) * 32 + q * 8);
#pragma unroll
        for (int nt = 0; nt < 8; nt++) {
            bf16x8 bf = *reinterpret_cast<const bf16x8*>(Bs + (nt * 16 + cl) * 32 + q * 8);
            acc[nt] = __builtin_amdgcn_mfma_f32_16x16x32_bf16(af, bf, acc[nt], 0, 0, 0);
        }
        __syncthreads();
    }
#pragma unroll
    for (int nt = 0; nt < 8; nt++) {
        int col = n0 + nt * 16 + cl;
        float bv_ = bias[col];
#pragma unroll
        for (int r = 0; r < 4; r++) {
            int row = m0 + w * 16 + q * 4 + r;
            Cout[(size_t)row * 512 + col] = f2bu((acc[nt][r] + bv_) * scale);
        }
    }
}

// ---------------- V -> V^T  ([b,h,d,n] so PV B-fragments are contiguous) ----------------
__global__ void k_vt(const unsigned short* __restrict__ Vb, unsigned short* __restrict__ Vt) {
    int s = blockIdx.y;            // s = b*8 + h
    int b = s >> 3, h = s & 7;
    int n0 = blockIdx.x * 64;
    __shared__ unsigned short T[64][66];
    int c = threadIdx.x & 63, r0 = threadIdx.x >> 6;
#pragma unroll
    for (int i = 0; i < 16; i++) {
        int r = r0 + i * 4;
        T[r][c] = Vb[(size_t)(b * 2048 + n0 + r) * 512 + h * 64 + c];
    }
    __syncthreads();
#pragma unroll
    for (int i = 0; i < 16; i++) {
        int a = r0 + i * 4;
        Vt[(size_t)(s * 64 + a) * 2048 + n0 + c] = T[c][a];
    }
}

// ---------------- flash attention: independent 16-row x 1024-col strip per wave ----------------
// 1024 blocks x 256 thr. bid = ((h*2+b)*32+it)*2+js (h-siblings share XCD for mperm L2 reuse).
// Wave w owns rows [it*64+w*16, +16), cols [js*1024, +1024) = 16 j-tiles. No in-loop barrier.
// p = exp2(S)*m (fixed-M folded into m); partial O (bf16, lane-packed) + lsum -> ws; k_comb finishes.
__global__ __launch_bounds__(256, 4) void k_attn(
    const unsigned short* __restrict__ Qs, const unsigned short* __restrict__ Kb,
    const unsigned short* __restrict__ Vt, const unsigned short* __restrict__ mp,
    unsigned short* __restrict__ PO, float* __restrict__ PL) {
    __shared__ __align__(16) unsigned short P[4][16 * 68];  // stride 68: conflict-free writes
    int bid = blockIdx.x;
    int js = bid & 1, it = (bid >> 1) & 31, b = (bid >> 6) & 1, h = bid >> 7;
    int tid = threadIdx.x, w = tid >> 6, l = tid & 63, q = l >> 4, cl = l & 15;
    int ic = it * 4 + w;                  // 16-row chunk id within batch b
    int rowg = b * 2048 + ic * 16;        // global row base for this wave

    // Q fragments (A-layout: m=cl, k=q*8+j), pre-scaled by log2e/8
    bf16x8 qf0, qf1;
    {
        const unsigned short* qp = Qs + (size_t)(rowg + cl) * 512 + h * 64 + q * 8;
        qf0 = *reinterpret_cast<const bf16x8*>(qp);
        qf1 = *reinterpret_cast<const bf16x8*>(qp + 32);
    }
    f32x4 O[4];
    float lsum[4];
#pragma unroll
    for (int nt = 0; nt < 4; nt++)
#pragma unroll
        for (int r = 0; r < 4; r++) O[nt][r] = 0.f;
#pragma unroll
    for (int r = 0; r < 4; r++) lsum[r] = 0.f;

    const unsigned short* Kh = Kb + (size_t)b * 2048 * 512 + h * 64;
    const unsigned short* Vh = Vt + ((size_t)(b * 8 + h) * 64) * 2048;
    const unsigned short* mb = mp + (size_t)(b * 128 + ic) * 32768 + l * 16;
    unsigned short* pw = &P[w][0];
    int j0 = js * 1024;

#pragma unroll 2
    for (int t = 0; t < 16; t++) {
        int jb = j0 + t * 64;
        int jt = js * 16 + t;
        // multiplier fragments (16 bf16/lane, contiguous)
        u16x8 mh0 = *reinterpret_cast<const u16x8*>(mb + (size_t)jt * 1024);
        u16x8 mh1 = *reinterpret_cast<const u16x8*>(mb + (size_t)jt * 1024 + 8);
        // S = (Q*log2e/8) K^T
        f32x4 S[4];
#pragma unroll
        for (int nt = 0; nt < 4; nt++) {
            const unsigned short* kp = Kh + (size_t)(jb + 16 * nt + cl) * 512 + q * 8;
            bf16x8 kf0 = *reinterpret_cast<const bf16x8*>(kp);
            bf16x8 kf1 = *reinterpret_cast<const bf16x8*>(kp + 32);
#pragma unroll
            for (int r = 0; r < 4; r++) S[nt][r] = 0.f;
            S[nt] = __builtin_amdgcn_mfma_f32_16x16x32_bf16(qf0, kf0, S[nt], 0, 0, 0);
            S[nt] = __builtin_amdgcn_mfma_f32_16x16x32_bf16(qf1, kf1, S[nt], 0, 0, 0);
        }
        // p = exp2(S) * m; per-lane row partial sums
#pragma unroll
        for (int r = 0; r < 4; r++)
#pragma unroll
            for (int nt = 0; nt < 4; nt++) {
                float mv = bu2f((r < 2) ? mh0[r * 4 + nt] : mh1[(r & 1) * 4 + nt]);
                float p = fexp2(S[nt][r]) * mv;
                S[nt][r] = p;
                lsum[r] += p;
            }
        // V fragments (consumed after P round-trip; issue now to overlap)
        bf16x8 vf[4][2];
#pragma unroll
        for (int nt = 0; nt < 4; nt++) {
            const unsigned short* vp = Vh + (size_t)(16 * nt + cl) * 2048 + jb + q * 8;
            vf[nt][0] = *reinterpret_cast<const bf16x8*>(vp);
            vf[nt][1] = *reinterpret_cast<const bf16x8*>(vp + 32);
        }
        // P: C/D layout -> A layout via per-wave LDS (wave-local; no barrier)
#pragma unroll
        for (int nt = 0; nt < 4; nt++)
#pragma unroll
            for (int r = 0; r < 4; r++)
                pw[(q * 4 + r) * 68 + 16 * nt + cl] = f2bu(S[nt][r]);
        bf16x8 pf0 = *reinterpret_cast<const bf16x8*>(pw + cl * 68 + q * 8);
        bf16x8 pf1 = *reinterpret_cast<const bf16x8*>(pw + cl * 68 + 32 + q * 8);
        // O += P V
#pragma unroll
        for (int nt = 0; nt < 4; nt++) {
            O[nt] = __builtin_amdgcn_mfma_f32_16x16x32_bf16(pf0, vf[nt][0], O[nt], 0, 0, 0);
            O[nt] = __builtin_amdgcn_mfma_f32_16x16x32_bf16(pf1, vf[nt][1], O[nt], 0, 0, 0);
        }
    }

    // reduce row sums over the 16 cl lanes (q preserved)
#pragma unroll
    for (int r = 0; r < 4; r++) {
        lsum[r] += __shfl_xor(lsum[r], 1, 64);
        lsum[r] += __shfl_xor(lsum[r], 2, 64);
        lsum[r] += __shfl_xor(lsum[r], 4, 64);
        lsum[r] += __shfl_xor(lsum[r], 8, 64);
    }
    size_t slab = (size_t)(((b * 8 + h) * 32 + it) * 2 + js);
    // partial O, bf16, lane-packed (matches mperm perm): slab*4096 + w*1024 + l*16 + r*4 + nt
    unsigned short* po = PO + slab * 4096 + w * 1024 + l * 16;
#pragma unroll
    for (int r = 0; r < 4; r++) {
        ushort4 o;
        o.x = f2bu(O[0][r]); o.y = f2bu(O[1][r]); o.z = f2bu(O[2][r]); o.w = f2bu(O[3][r]);
        *reinterpret_cast<ushort4*>(po + r * 4) = o;
    }
    if (cl == 0) {
#pragma unroll
        for (int r = 0; r < 4; r++)
            PL[slab * 64 + w * 16 + q * 4 + r] = lsum[r];
    }
}

// ---------------- combine j-halves, normalize, residual ----------------
// 512 blocks ((b*8+h)*32+it) x 256 thr. Reads lane-packed bf16 partials coalesced.
__global__ void k_comb(const unsigned short* __restrict__ PO, const float* __restrict__ PL,
                       const float* __restrict__ x, float* __restrict__ out) {
    int blk = blockIdx.x;
    int it = blk & 31, h = (blk >> 5) & 7, b = blk >> 8;
    int t = threadIdx.x;               // t = l*4 + r
    const unsigned short* s0 = PO + (size_t)blk * 8192;
    const unsigned short* s1 = s0 + 4096;
    const float* L0 = PL + (size_t)blk * 128;
    const float* L1 = L0 + 64;
    int l = t >> 2, r = t & 3, q = l >> 4, cl = l & 15;
#pragma unroll
    for (int w = 0; w < 4; w++) {
        int idx = w * 1024 + t * 4;
        int row = w * 16 + q * 4 + r;
        ushort4 a = *reinterpret_cast<const ushort4*>(s0 + idx);
        ushort4 c = *reinterpret_cast<const ushort4*>(s1 + idx);
        float inv = 1.0f / (L0[row] + L1[row]);
        size_t gro = (size_t)(b * 2048 + it * 64 + row) * 512 + h * 64;
        out[gro + 0 * 16 + cl] = (bu2f(a.x) + bu2f(c.x)) * inv + x[gro + 0 * 16 + cl];
        out[gro + 1 * 16 + cl] = (bu2f(a.y) + bu2f(c.y)) * inv + x[gro + 1 * 16 + cl];
        out[gro + 2 * 16 + cl] = (bu2f(a.z) + bu2f(c.z)) * inv + x[gro + 2 * 16 + cl];
        out[gro + 3 * 16 + cl] = (bu2f(a.w) + bu2f(c.w)) * inv + x[gro + 3 * 16 + cl];
    }
}

extern "C" void kernel_launch(void* const* d_in, const int* in_sizes, int n_in,
                              void* d_out, int out_size, void* d_ws, size_t ws_size,
                              hipStream_t stream) {
    const float* x   = (const float*)d_in[0];
    const float* adj = (const float*)d_in[1];
    const float* Wq  = (const float*)d_in[2];
    const float* bq  = (const float*)d_in[3];
    const float* Wk  = (const float*)d_in[4];
    const float* bk  = (const float*)d_in[5];
    const float* Wv  = (const float*)d_in[6];
    const float* bv  = (const float*)d_in[7];
    const float* wg  = (const float*)d_in[8];
    // d_in[9] (b_g) unused: row-constant bias cancels in softmax
    float* out = (float*)d_out;
    char* ws = (char*)d_ws;
    unsigned short* Qs = (unsigned short*)(ws + OFF_QS);
    unsigned short* Kb = (unsigned short*)(ws + OFF_KB);
    unsigned short* Vt = (unsigned short*)(ws + OFF_VT);
    float* cv2 = (float*)(ws + OFF_CV);
    unsigned short* mpm = (unsigned short*)(ws + OFF_MP);
    unsigned short* PO = (unsigned short*)(ws + OFF_PO);
    float* PL = (float*)(ws + OFF_PL);
    unsigned short* xb = (unsigned short*)(ws + OFF_XB);
    unsigned short* wt = (unsigned short*)(ws + OFF_WT);
    unsigned short* Vb = (unsigned short*)(ws + OFF_VB);

    k_prep<<<1024, 256, 0, stream>>>(x, wg, xb, cv2);
    k_wt<<<dim3(3, 64), 256, 0, stream>>>(Wq, Wk, Wv, wt);
    k_gemm<<<dim3(64, 4, 3), 256, 0, stream>>>(xb, wt, bq, bk, bv, Qs, Kb, Vb);
    k_vt<<<dim3(32, 16), 256, 0, stream>>>(Vb, Vt);
    k_adjp<<<8192, 256, 0, stream>>>(adj, cv2, mpm);   // clobbers xb/wt/Vb (dead)
    k_attn<<<1024, 256, 0, stream>>>(Qs, Kb, Vt, mpm, PO, PL);
    k_comb<<<512, 256, 0, stream>>>(PO, PL, x, out);
}

// Round 5
// 168.247 us; speedup vs baseline: 1.5920x; 1.4543x over previous
//
#include <hip/hip_runtime.h>
#include <hip/hip_bf16.h>

// Problem constants: B=2, N=2048, D=512, H=8, hd=64
typedef __bf16 bf16x8 __attribute__((ext_vector_type(8)));
typedef float f32x4 __attribute__((ext_vector_type(4)));
typedef unsigned short u16x8 __attribute__((ext_vector_type(8)));

#define LOG2E 1.44269504f

__device__ __forceinline__ unsigned short f2bu(float f) {
    __hip_bfloat16 h = __float2bfloat16(f);
    unsigned short u;
    __builtin_memcpy(&u, &h, 2);
    return u;
}

__device__ __forceinline__ float fexp2(float x) {
#if __has_builtin(__builtin_amdgcn_exp2f)
    return __builtin_amdgcn_exp2f(x);
#else
    return __expf(x * 0.69314718f);
#endif
}

__device__ __forceinline__ float bu2f(unsigned short u) {
    unsigned int v = ((unsigned int)u) << 16;
    float f;
    __builtin_memcpy(&f, &v, 4);
    return f;
}

// async global->LDS, 16B per lane. LDS base must be wave-uniform; HW appends lane*16.
#define GLDS16(gp, lp) __builtin_amdgcn_global_load_lds( \
    (const __attribute__((address_space(1))) unsigned int*)(gp), \
    (__attribute__((address_space(3))) unsigned int*)(lp), 16, 0, 0)

// ---- workspace layout (bytes). xb/wt transient, overlaid on mperm region.
#define OFF_QS  0u                          // Q*(0.125*log2e) bf16  4 MB
#define OFF_KB  4194304u                    // K bf16                4 MB
#define OFF_VT  8388608u                    // V^T [b,h,d,n] bf16    4 MB
#define OFF_CV  12582912u                   // cv2[b,n] f32 = 2^((c-8)*log2e)  16 KB
#define OFF_MP  12648448u                   // m permuted bf16       16.78 MB (ends 29425664)
#define OFF_PO  29425664u                   // partial O bf16, 4096 chunks x 1024  8.39 MB
#define OFF_PL  37814272u                   // partial lsum f32, 4096 chunks x 16  256 KB
#define OFF_XB  OFF_MP                      // x bf16 (transient)    4 MB
#define OFF_WT  (OFF_MP + 4194304u)         // W^T bf16 (transient)  1.5 MB

// ---------------- prep (merged): x->bf16 + cv2, and Wt[n][k] = bf16(W[k][n]) ----------------
__global__ void k_prepwt(const float* __restrict__ x, const float* __restrict__ wg,
                         const float* __restrict__ w0, const float* __restrict__ w1,
                         const float* __restrict__ w2,
                         unsigned short* __restrict__ xb, float* __restrict__ cv2,
                         unsigned short* __restrict__ wt) {
    if (blockIdx.x < 1024) {
        int row = blockIdx.x * 4 + (threadIdx.x >> 6);   // 4096 rows
        int l = threadIdx.x & 63;
        const float4* xr = reinterpret_cast<const float4*>(x + (size_t)row * 512);
        float4 a = xr[l * 2], b2 = xr[l * 2 + 1];
        ushort4 o0, o1;
        o0.x = f2bu(a.x);  o0.y = f2bu(a.y);  o0.z = f2bu(a.z);  o0.w = f2bu(a.w);
        o1.x = f2bu(b2.x); o1.y = f2bu(b2.y); o1.z = f2bu(b2.z); o1.w = f2bu(b2.w);
        ushort4* dst = reinterpret_cast<ushort4*>(xb + (size_t)row * 512);
        dst[l * 2] = o0; dst[l * 2 + 1] = o1;
        const float4* wr = reinterpret_cast<const float4*>(wg + 512);
        float4 g0 = wr[l * 2], g1 = wr[l * 2 + 1];
        float s = a.x * g0.x + a.y * g0.y + a.z * g0.z + a.w * g0.w
                + b2.x * g1.x + b2.y * g1.y + b2.z * g1.z + b2.w * g1.w;
#pragma unroll
        for (int off = 32; off >= 1; off >>= 1) s += __shfl_xor(s, off, 64);
        if (l == 0) cv2[row] = fexp2((s - 8.0f) * LOG2E);
    } else {
        int bid2 = blockIdx.x - 1024;        // 192 blocks: z*64 + yy
        int z = bid2 >> 6, yy = bid2 & 63;
        int k0 = (yy >> 3) * 64, n0 = (yy & 7) * 64;
        const float* W = (z == 0) ? w0 : ((z == 1) ? w1 : w2);
        __shared__ float T[64][65];
        int c = threadIdx.x & 63, r0 = threadIdx.x >> 6;
#pragma unroll
        for (int i = 0; i < 16; i++) { int r = r0 + i * 4; T[r][c] = W[(k0 + r) * 512 + n0 + c]; }
        __syncthreads();
        unsigned short* Wt = wt + z * (512 * 512);
#pragma unroll
        for (int i = 0; i < 16; i++) { int a = r0 + i * 4; Wt[(n0 + a) * 512 + k0 + c] = f2bu(T[c][a]); }
    }
}

// ---------------- prep: mperm = bf16((adj+eps)*cv2[j]) in MFMA-lane order ----------------
// mperm[bic*32768 + jt*1024 + l*16 + r*4 + nt] = m[b][ic*16+q*4+r][jt*64+nt*16+cl], l=q*16+cl
__global__ void k_adjp(const float* __restrict__ adj, const float* __restrict__ cv2,
                       unsigned short* __restrict__ mp) {
    int blk = blockIdx.x;              // bic*32 + jt
    int bic = blk >> 5, jt = blk & 31;
    int b = bic >> 7, ic = bic & 127;
    int t = threadIdx.x;               // 256: t = l*4 + r
    int l = t >> 2, r = t & 3, q = l >> 4, cl = l & 15;
    int row = ic * 16 + q * 4 + r;
    const float* ar = adj + ((size_t)(b * 2048 + row)) * 2048 + jt * 64;
    const float* cb = cv2 + b * 2048 + jt * 64;
    ushort4 o;
    o.x = f2bu((ar[cl]      + 1e-9f) * cb[cl]);
    o.y = f2bu((ar[16 + cl] + 1e-9f) * cb[16 + cl]);
    o.z = f2bu((ar[32 + cl] + 1e-9f) * cb[32 + cl]);
    o.w = f2bu((ar[48 + cl] + 1e-9f) * cb[48 + cl]);
    *reinterpret_cast<ushort4*>(mp + (size_t)bic * 32768 + jt * 1024 + t * 4) = o;
}

// ---------------- fused QKV projection GEMM; z==2 writes V^T [b,h,d,n] directly ----------------
__global__ __launch_bounds__(256) void k_gemm(
    const unsigned short* __restrict__ xb, const unsigned short* __restrict__ wt,
    const float* __restrict__ bq, const float* __restrict__ bk, const float* __restrict__ bv,
    unsigned short* __restrict__ Qs, unsigned short* __restrict__ Kb,
    unsigned short* __restrict__ Vt) {
    __shared__ __align__(16) unsigned short As[64 * 32];
    __shared__ __align__(16) unsigned short Bs[128 * 32];
    int z = blockIdx.z;
    const unsigned short* Wt = wt + z * (512 * 512);
    const float* bias = (z == 0) ? bq : ((z == 1) ? bk : bv);
    float scale = (z == 0) ? (0.125f * LOG2E) : 1.0f;   // Q pre-scaled by log2e/sqrt(64)
    int m0 = blockIdx.x * 64, n0 = blockIdx.y * 128;
    int tid = threadIdx.x, w = tid >> 6, l = tid & 63;
    int q = l >> 4, cl = l & 15;
    f32x4 acc[8];
#pragma unroll
    for (int nt = 0; nt < 8; nt++)
#pragma unroll
        for (int r = 0; r < 4; r++) acc[nt][r] = 0.f;

    int arow = l >> 2, ach = (l & 3) * 8;
    for (int k0 = 0; k0 < 512; k0 += 32) {
        GLDS16(xb + (size_t)(m0 + w * 16 + arow) * 512 + k0 + ach, As + w * 512);
#pragma unroll
        for (int e = 0; e < 2; e++)
            GLDS16(Wt + (size_t)(n0 + w * 32 + e * 16 + arow) * 512 + k0 + ach, Bs + w * 1024 + e * 512);
        __syncthreads();
        bf16x8 af = *reinterpret_cast<const bf16x8*>(As + (w * 16 + cl) * 32 + q * 8);
#pragma unroll
        for (int nt = 0; nt < 8; nt++) {
            bf16x8 bf = *reinterpret_cast<const bf16x8*>(Bs + (nt * 16 + cl) * 32 + q * 8);
            acc[nt] = __builtin_amdgcn_mfma_f32_16x16x32_bf16(af, bf, acc[nt], 0, 0, 0);
        }
        __syncthreads();
    }
    if (z == 2) {
        // V^T: row=(b,n), col=(h,d) -> Vt[((b*8+h)*64+d)*2048 + n]; 4 consecutive n pack to ushort4
        int n_ = (m0 + w * 16 + q * 4) & 2047;
        int b_ = (m0 + w * 16) >> 11;
#pragma unroll
        for (int nt = 0; nt < 8; nt++) {
            int col = n0 + nt * 16 + cl;
            int h_ = col >> 6, d_ = col & 63;
            float bv_ = bias[col];
            ushort4 o;
            o.x = f2bu(acc[nt][0] + bv_); o.y = f2bu(acc[nt][1] + bv_);
            o.z = f2bu(acc[nt][2] + bv_); o.w = f2bu(acc[nt][3] + bv_);
            *reinterpret_cast<ushort4*>(Vt + ((size_t)((b_ * 8 + h_) * 64 + d_)) * 2048 + n_) = o;
        }
    } else {
        unsigned short* Cout = (z == 0) ? Qs : Kb;
#pragma unroll
        for (int nt = 0; nt < 8; nt++) {
            int col = n0 + nt * 16 + cl;
            float bv_ = bias[col];
#pragma unroll
            for (int r = 0; r < 4; r++) {
                int row = m0 + w * 16 + q * 4 + r;
                Cout[(size_t)row * 512 + col] = f2bu((acc[nt][r] + bv_) * scale);
            }
        }
    }
}

// ---------------- flash attention: LDS-staged K/V (m97 pattern), 32 rows/wave ----------------
// 512 blocks x 256 thr. bid: js=bit0, it=bits1-4 (128-row tile), b=bit5, h=bits6-8.
// Wave w: rows [it*128+w*32,+32) as 2 chunks rc. j-loop: 16 tiles of 64 (half js).
// Per iter: stage K(8KB)+V(8KB) tile into LDS via GLDS16 (4/wave), fragments via ds_read_b128.
// p = exp2(S)*m (fixed-M folded into m); partial O bf16 + lsum -> ws; k_comb finishes.
__global__ __launch_bounds__(256, 2) void k_attn(
    const unsigned short* __restrict__ Qs, const unsigned short* __restrict__ Kb,
    const unsigned short* __restrict__ Vt, const unsigned short* __restrict__ mp,
    unsigned short* __restrict__ PO, float* __restrict__ PL) {
    __shared__ __align__(16) unsigned short Ks[4096];   // [kk][64 rows][32 elems]
    __shared__ __align__(16) unsigned short Vs[4096];   // [jj][64 drow][32 elems]
    __shared__ __align__(16) unsigned short P[4][32 * 68];
    int bid = blockIdx.x;
    int js = bid & 1, it = (bid >> 1) & 15, b = (bid >> 5) & 1, h = bid >> 6;
    int tid = threadIdx.x, w = tid >> 6, l = tid & 63, q = l >> 4, cl = l & 15;
    int bh = b * 8 + h;
    int rowbase = it * 128 + w * 32;          // within batch b

    // Q fragments for 2 row-chunks (A-layout: m=cl, k=kk*32+q*8+j), pre-scaled by log2e/8
    bf16x8 qf[2][2];
#pragma unroll
    for (int rc = 0; rc < 2; rc++) {
        const unsigned short* qp = Qs + (size_t)(b * 2048 + rowbase + rc * 16 + cl) * 512 + h * 64 + q * 8;
        qf[rc][0] = *reinterpret_cast<const bf16x8*>(qp);
        qf[rc][1] = *reinterpret_cast<const bf16x8*>(qp + 32);
    }
    f32x4 O[2][4];
    float lsum[2][4];
#pragma unroll
    for (int rc = 0; rc < 2; rc++) {
#pragma unroll
        for (int nt = 0; nt < 4; nt++)
#pragma unroll
            for (int r = 0; r < 4; r++) O[rc][nt][r] = 0.f;
#pragma unroll
        for (int r = 0; r < 4; r++) lsum[rc][r] = 0.f;
    }

    const unsigned short* Kh = Kb + (size_t)b * 2048 * 512 + h * 64;
    const unsigned short* Vh = Vt + ((size_t)bh * 64) * 2048;
    // mperm bases: ic = it*8 + w*2 + rc
    const unsigned short* mb0 = mp + ((size_t)(b * 128 + it * 8 + w * 2 + 0)) * 32768 + l * 16;
    const unsigned short* mb1 = mp + ((size_t)(b * 128 + it * 8 + w * 2 + 1)) * 32768 + l * 16;
    unsigned short* pw = &P[w][0];
    int lrow = l >> 2, lch = (l & 3) * 8;     // staging: lane -> row/4, 16B chunk

    for (int t = 0; t < 16; t++) {
        int jb = js * 1024 + t * 64;
        int jt = js * 16 + t;
        // stage K and V tiles: chunk c = w*2+e covers [kk=c>>2][16 rows=(c&3)*16][32 elems]
#pragma unroll
        for (int e = 0; e < 2; e++) {
            int c = w * 2 + e, kk = c >> 2, r16 = (c & 3) * 16;
            GLDS16(Kh + (size_t)(jb + r16 + lrow) * 512 + kk * 32 + lch, Ks + kk * 2048 + r16 * 32);
            GLDS16(Vh + (size_t)(r16 + lrow) * 2048 + jb + kk * 32 + lch, Vs + kk * 2048 + r16 * 32);
        }
        // m fragments (regs; drained by the same barrier)
        u16x8 mh[2][2];
        mh[0][0] = *reinterpret_cast<const u16x8*>(mb0 + (size_t)jt * 1024);
        mh[0][1] = *reinterpret_cast<const u16x8*>(mb0 + (size_t)jt * 1024 + 8);
        mh[1][0] = *reinterpret_cast<const u16x8*>(mb1 + (size_t)jt * 1024);
        mh[1][1] = *reinterpret_cast<const u16x8*>(mb1 + (size_t)jt * 1024 + 8);
        __syncthreads();   // staging complete
        // S = (Q*log2e/8) K^T from LDS
        f32x4 S[2][4];
#pragma unroll
        for (int rc = 0; rc < 2; rc++)
#pragma unroll
            for (int r = 0; r < 4; r++) S[rc][0][r] = S[rc][1][r] = S[rc][2][r] = S[rc][3][r] = 0.f;
#pragma unroll
        for (int nt = 0; nt < 4; nt++) {
            bf16x8 kf0 = *reinterpret_cast<const bf16x8*>(Ks + (16 * nt + cl) * 32 + q * 8);
            bf16x8 kf1 = *reinterpret_cast<const bf16x8*>(Ks + 2048 + (16 * nt + cl) * 32 + q * 8);
#pragma unroll
            for (int rc = 0; rc < 2; rc++) {
                S[rc][nt] = __builtin_amdgcn_mfma_f32_16x16x32_bf16(qf[rc][0], kf0, S[rc][nt], 0, 0, 0);
                S[rc][nt] = __builtin_amdgcn_mfma_f32_16x16x32_bf16(qf[rc][1], kf1, S[rc][nt], 0, 0, 0);
            }
        }
        // p = exp2(S)*m; per-lane row sums; P -> LDS (A-layout round-trip)
#pragma unroll
        for (int rc = 0; rc < 2; rc++)
#pragma unroll
            for (int r = 0; r < 4; r++)
#pragma unroll
                for (int nt = 0; nt < 4; nt++) {
                    float mv = bu2f((r < 2) ? mh[rc][0][r * 4 + nt] : mh[rc][1][(r & 1) * 4 + nt]);
                    float p = fexp2(S[rc][nt][r]) * mv;
                    lsum[rc][r] += p;
                    pw[(rc * 16 + q * 4 + r) * 68 + 16 * nt + cl] = f2bu(p);
                }
        // O += P V from LDS
#pragma unroll
        for (int rc = 0; rc < 2; rc++) {
            bf16x8 pf0 = *reinterpret_cast<const bf16x8*>(pw + (rc * 16 + cl) * 68 + q * 8);
            bf16x8 pf1 = *reinterpret_cast<const bf16x8*>(pw + (rc * 16 + cl) * 68 + 32 + q * 8);
#pragma unroll
            for (int nt = 0; nt < 4; nt++) {
                bf16x8 vf0 = *reinterpret_cast<const bf16x8*>(Vs + (16 * nt + cl) * 32 + q * 8);
                bf16x8 vf1 = *reinterpret_cast<const bf16x8*>(Vs + 2048 + (16 * nt + cl) * 32 + q * 8);
                O[rc][nt] = __builtin_amdgcn_mfma_f32_16x16x32_bf16(pf0, vf0, O[rc][nt], 0, 0, 0);
                O[rc][nt] = __builtin_amdgcn_mfma_f32_16x16x32_bf16(pf1, vf1, O[rc][nt], 0, 0, 0);
            }
        }
        __syncthreads();   // all waves done reading Ks/Vs before next staging
    }

    // reduce row sums over the 16 cl lanes (q preserved)
#pragma unroll
    for (int rc = 0; rc < 2; rc++)
#pragma unroll
        for (int r = 0; r < 4; r++) {
            lsum[rc][r] += __shfl_xor(lsum[rc][r], 1, 64);
            lsum[rc][r] += __shfl_xor(lsum[rc][r], 2, 64);
            lsum[rc][r] += __shfl_xor(lsum[rc][r], 4, 64);
            lsum[rc][r] += __shfl_xor(lsum[rc][r], 8, 64);
        }
#pragma unroll
    for (int rc = 0; rc < 2; rc++) {
        size_t chunk = ((size_t)(bh * 128 + it * 8 + w * 2 + rc)) * 2 + js;
        unsigned short* po = PO + chunk * 1024 + l * 16;
#pragma unroll
        for (int r = 0; r < 4; r++) {
            ushort4 o;
            o.x = f2bu(O[rc][0][r]); o.y = f2bu(O[rc][1][r]);
            o.z = f2bu(O[rc][2][r]); o.w = f2bu(O[rc][3][r]);
            *reinterpret_cast<ushort4*>(po + r * 4) = o;
        }
        if (cl == 0) {
#pragma unroll
            for (int r = 0; r < 4; r++)
                PL[chunk * 16 + q * 4 + r] = lsum[rc][r];
        }
    }
}

// ---------------- combine j-halves, normalize, residual ----------------
// 512 blocks (bh*32 + t64) x 256 thr; each block 4 row-chunks (64 rows).
__global__ void k_comb(const unsigned short* __restrict__ PO, const float* __restrict__ PL,
                       const float* __restrict__ x, float* __restrict__ out) {
    int blk = blockIdx.x;
    int t64 = blk & 31, bh = blk >> 5;
    int b = bh >> 3, h = bh & 7;
    int t = threadIdx.x;               // t = l*4 + r
    int l = t >> 2, r = t & 3, q = l >> 4, cl = l & 15;
#pragma unroll
    for (int w = 0; w < 4; w++) {
        int ic = t64 * 4 + w;
        size_t c0 = ((size_t)(bh * 128 + ic)) * 2;
        ushort4 a = *reinterpret_cast<const ushort4*>(PO + c0 * 1024 + t * 4);
        ushort4 c = *reinterpret_cast<const ushort4*>(PO + (c0 + 1) * 1024 + t * 4);
        float inv = 1.0f / (PL[c0 * 16 + q * 4 + r] + PL[(c0 + 1) * 16 + q * 4 + r]);
        size_t gro = (size_t)(b * 2048 + ic * 16 + q * 4 + r) * 512 + h * 64;
        out[gro + 0 * 16 + cl] = (bu2f(a.x) + bu2f(c.x)) * inv + x[gro + 0 * 16 + cl];
        out[gro + 1 * 16 + cl] = (bu2f(a.y) + bu2f(c.y)) * inv + x[gro + 1 * 16 + cl];
        out[gro + 2 * 16 + cl] = (bu2f(a.z) + bu2f(c.z)) * inv + x[gro + 2 * 16 + cl];
        out[gro + 3 * 16 + cl] = (bu2f(a.w) + bu2f(c.w)) * inv + x[gro + 3 * 16 + cl];
    }
}

extern "C" void kernel_launch(void* const* d_in, const int* in_sizes, int n_in,
                              void* d_out, int out_size, void* d_ws, size_t ws_size,
                              hipStream_t stream) {
    const float* x   = (const float*)d_in[0];
    const float* adj = (const float*)d_in[1];
    const float* Wq  = (const float*)d_in[2];
    const float* bq  = (const float*)d_in[3];
    const float* Wk  = (const float*)d_in[4];
    const float* bk  = (const float*)d_in[5];
    const float* Wv  = (const float*)d_in[6];
    const float* bv  = (const float*)d_in[7];
    const float* wg  = (const float*)d_in[8];
    // d_in[9] (b_g) unused: row-constant bias cancels in softmax
    float* out = (float*)d_out;
    char* ws = (char*)d_ws;
    unsigned short* Qs = (unsigned short*)(ws + OFF_QS);
    unsigned short* Kb = (unsigned short*)(ws + OFF_KB);
    unsigned short* Vt = (unsigned short*)(ws + OFF_VT);
    float* cv2 = (float*)(ws + OFF_CV);
    unsigned short* mpm = (unsigned short*)(ws + OFF_MP);
    unsigned short* PO = (unsigned short*)(ws + OFF_PO);
    float* PL = (float*)(ws + OFF_PL);
    unsigned short* xb = (unsigned short*)(ws + OFF_XB);
    unsigned short* wt = (unsigned short*)(ws + OFF_WT);

    k_prepwt<<<1216, 256, 0, stream>>>(x, wg, Wq, Wk, Wv, xb, cv2, wt);
    k_gemm<<<dim3(64, 4, 3), 256, 0, stream>>>(xb, wt, bq, bk, bv, Qs, Kb, Vt);
    k_adjp<<<8192, 256, 0, stream>>>(adj, cv2, mpm);   // clobbers xb/wt (dead)
    k_attn<<<512, 256, 0, stream>>>(Qs, Kb, Vt, mpm, PO, PL);
    k_comb<<<512, 256, 0, stream>>>(PO, PL, x, out);
}

// Round 6
// 159.736 us; speedup vs baseline: 1.6768x; 1.0533x over previous
//
#include <hip/hip_runtime.h>
#include <hip/hip_bf16.h>

// Problem constants: B=2, N=2048, D=512, H=8, hd=64
typedef __bf16 bf16x8 __attribute__((ext_vector_type(8)));
typedef float f32x4 __attribute__((ext_vector_type(4)));
typedef unsigned short u16x8 __attribute__((ext_vector_type(8)));

#define LOG2E 1.44269504f

__device__ __forceinline__ unsigned short f2bu(float f) {
    __hip_bfloat16 h = __float2bfloat16(f);
    unsigned short u;
    __builtin_memcpy(&u, &h, 2);
    return u;
}

__device__ __forceinline__ float fexp2(float x) {
#if __has_builtin(__builtin_amdgcn_exp2f)
    return __builtin_amdgcn_exp2f(x);
#else
    return __expf(x * 0.69314718f);
#endif
}

__device__ __forceinline__ float bu2f(unsigned short u) {
    unsigned int v = ((unsigned int)u) << 16;
    float f;
    __builtin_memcpy(&f, &v, 4);
    return f;
}

// async global->LDS, 16B per lane. LDS base must be wave-uniform; HW appends lane*16.
#define GLDS16(gp, lp) __builtin_amdgcn_global_load_lds( \
    (const __attribute__((address_space(1))) unsigned int*)(gp), \
    (__attribute__((address_space(3))) unsigned int*)(lp), 16, 0, 0)

// ---- workspace layout (bytes). No overlays: adjp runs concurrently with gemm.
#define OFF_QS  0u                          // Q*(0.125*log2e) bf16  4 MB
#define OFF_KB  4194304u                    // K bf16                4 MB
#define OFF_VT  8388608u                    // V^T [b,h,d,n] bf16    4 MB
#define OFF_CV  12582912u                   // cv2[b,n] f32 = 2^((c-8)*log2e)  16 KB
#define OFF_XB  12599296u                   // x bf16                4 MB
#define OFF_WT  16793600u                   // W^T bf16              1.5 MB
#define OFF_MQ  18366464u                   // m transposed-perm bf16 16.78 MB (ends 35.1 MB)

// ---------------- prep (merged): x->bf16 + cv2, and Wt[n][k] = bf16(W[k][n]) ----------------
__global__ void k_prepwt(const float* __restrict__ x, const float* __restrict__ wg,
                         const float* __restrict__ w0, const float* __restrict__ w1,
                         const float* __restrict__ w2,
                         unsigned short* __restrict__ xb, float* __restrict__ cv2,
                         unsigned short* __restrict__ wt) {
    if (blockIdx.x < 1024) {
        int row = blockIdx.x * 4 + (threadIdx.x >> 6);   // 4096 rows
        int l = threadIdx.x & 63;
        const float4* xr = reinterpret_cast<const float4*>(x + (size_t)row * 512);
        float4 a = xr[l * 2], b2 = xr[l * 2 + 1];
        ushort4 o0, o1;
        o0.x = f2bu(a.x);  o0.y = f2bu(a.y);  o0.z = f2bu(a.z);  o0.w = f2bu(a.w);
        o1.x = f2bu(b2.x); o1.y = f2bu(b2.y); o1.z = f2bu(b2.z); o1.w = f2bu(b2.w);
        ushort4* dst = reinterpret_cast<ushort4*>(xb + (size_t)row * 512);
        dst[l * 2] = o0; dst[l * 2 + 1] = o1;
        const float4* wr = reinterpret_cast<const float4*>(wg + 512);
        float4 g0 = wr[l * 2], g1 = wr[l * 2 + 1];
        float s = a.x * g0.x + a.y * g0.y + a.z * g0.z + a.w * g0.w
                + b2.x * g1.x + b2.y * g1.y + b2.z * g1.z + b2.w * g1.w;
#pragma unroll
        for (int off = 32; off >= 1; off >>= 1) s += __shfl_xor(s, off, 64);
        if (l == 0) cv2[row] = fexp2((s - 8.0f) * LOG2E);
    } else {
        int bid2 = blockIdx.x - 1024;        // 192 blocks: z*64 + yy
        int z = bid2 >> 6, yy = bid2 & 63;
        int k0 = (yy >> 3) * 64, n0 = (yy & 7) * 64;
        const float* W = (z == 0) ? w0 : ((z == 1) ? w1 : w2);
        __shared__ float T[64][65];
        int c = threadIdx.x & 63, r0 = threadIdx.x >> 6;
#pragma unroll
        for (int i = 0; i < 16; i++) { int r = r0 + i * 4; T[r][c] = W[(k0 + r) * 512 + n0 + c]; }
        __syncthreads();
        unsigned short* Wt = wt + z * (512 * 512);
#pragma unroll
        for (int i = 0; i < 16; i++) { int a = r0 + i * 4; Wt[(n0 + a) * 512 + k0 + c] = f2bu(T[c][a]); }
    }
}

// ---------------- merged: adjp (transposed perm) + QKV GEMM ----------------
// adjp part (blocks 0..8191): mq[((b*128+ic)*32+jt)*1024 + l*16 + mt*4 + r]
//   = bf16((adj[b][ic*16+cl][j] + eps) * cv2[b][j]),  j = jt*64 + 16*mt + q*4 + r, l=q*16+cl.
//   Matches S^T C/D layout in k_attn: lane l holds (j_local=16mt+q*4+r, i_local=cl).
// gemm part (blocks 8192..8959): 64x128 tile QKV projection; z==2 writes V^T directly.
__global__ __launch_bounds__(256) void k_mid(
    const float* __restrict__ adj, const float* __restrict__ cv2,
    unsigned short* __restrict__ mq,
    const unsigned short* __restrict__ xb, const unsigned short* __restrict__ wt,
    const float* __restrict__ bq, const float* __restrict__ bk, const float* __restrict__ bv,
    unsigned short* __restrict__ Qs, unsigned short* __restrict__ Kb,
    unsigned short* __restrict__ Vt) {
    if (blockIdx.x < 8192) {
        int blk = blockIdx.x;              // bic*32 + jt
        int bic = blk >> 5, jt = blk & 31;
        int b = bic >> 7, ic = bic & 127;
        int t = threadIdx.x;               // t = l*4 + mt
        int l = t >> 2, mt = t & 3, q = l >> 4, cl = l & 15;
        int j0 = jt * 64 + 16 * mt + q * 4;
        const float4 av = *reinterpret_cast<const float4*>(
            adj + ((size_t)(b * 2048 + ic * 16 + cl)) * 2048 + j0);
        const float4 cv = *reinterpret_cast<const float4*>(cv2 + b * 2048 + j0);
        ushort4 o;
        o.x = f2bu((av.x + 1e-9f) * cv.x);
        o.y = f2bu((av.y + 1e-9f) * cv.y);
        o.z = f2bu((av.z + 1e-9f) * cv.z);
        o.w = f2bu((av.w + 1e-9f) * cv.w);
        *reinterpret_cast<ushort4*>(mq + (size_t)bic * 32768 + jt * 1024 + l * 16 + mt * 4) = o;
        return;
    }
    int gid = blockIdx.x - 8192;           // 768: x(64) y(4) z(3)
    int bx = gid & 63, by = (gid >> 6) & 3, z = gid >> 8;
    __shared__ __align__(16) unsigned short As[64 * 32];
    __shared__ __align__(16) unsigned short Bs[128 * 32];
    const unsigned short* Wt = wt + z * (512 * 512);
    const float* bias = (z == 0) ? bq : ((z == 1) ? bk : bv);
    float scale = (z == 0) ? (0.125f * LOG2E) : 1.0f;   // Q pre-scaled by log2e/sqrt(64)
    int m0 = bx * 64, n0 = by * 128;
    int tid = threadIdx.x, w = tid >> 6, l = tid & 63;
    int q = l >> 4, cl = l & 15;
    f32x4 acc[8];
#pragma unroll
    for (int nt = 0; nt < 8; nt++)
#pragma unroll
        for (int r = 0; r < 4; r++) acc[nt][r] = 0.f;
    int arow = l >> 2, ach = (l & 3) * 8;
    for (int k0 = 0; k0 < 512; k0 += 32) {
        GLDS16(xb + (size_t)(m0 + w * 16 + arow) * 512 + k0 + ach, As + w * 512);
#pragma unroll
        for (int e = 0; e < 2; e++)
            GLDS16(Wt + (size_t)(n0 + w * 32 + e * 16 + arow) * 512 + k0 + ach, Bs + w * 1024 + e * 512);
        __syncthreads();
        bf16x8 af = *reinterpret_cast<const bf16x8*>(As + (w * 16 + cl) * 32 + q * 8);
#pragma unroll
        for (int nt = 0; nt < 8; nt++) {
            bf16x8 bf = *reinterpret_cast<const bf16x8*>(Bs + (nt * 16 + cl) * 32 + q * 8);
            acc[nt] = __builtin_amdgcn_mfma_f32_16x16x32_bf16(af, bf, acc[nt], 0, 0, 0);
        }
        __syncthreads();
    }
    if (z == 2) {
        int n_ = (m0 + w * 16 + q * 4) & 2047;
        int b_ = (m0 + w * 16) >> 11;
#pragma unroll
        for (int nt = 0; nt < 8; nt++) {
            int col = n0 + nt * 16 + cl;
            int h_ = col >> 6, d_ = col & 63;
            float bv_ = bias[col];
            ushort4 o;
            o.x = f2bu(acc[nt][0] + bv_); o.y = f2bu(acc[nt][1] + bv_);
            o.z = f2bu(acc[nt][2] + bv_); o.w = f2bu(acc[nt][3] + bv_);
            *reinterpret_cast<ushort4*>(Vt + ((size_t)((b_ * 8 + h_) * 64 + d_)) * 2048 + n_) = o;
        }
    } else {
        unsigned short* Cout = (z == 0) ? Qs : Kb;
#pragma unroll
        for (int nt = 0; nt < 8; nt++) {
            int col = n0 + nt * 16 + cl;
            float bv_ = bias[col];
#pragma unroll
            for (int r = 0; r < 4; r++) {
                int row = m0 + w * 16 + q * 4 + r;
                Cout[(size_t)row * 512 + col] = f2bu((acc[nt][r] + bv_) * scale);
            }
        }
    }
}

// ---------------- flash attention, transposed-S formulation ----------------
// 512 blocks x 256 thr. bid = ig*16 + h*2 + b; wave w: rows [ig*64+w*16,+16), FULL j range.
// Per iter (64-j tile): stage K,V to LDS (GLDS16); S^T = K.Q^T (A=K staged, B=Q^T loop-invariant);
// p = exp2(S^T)*m (m pre-permuted to S^T C/D layout); P -> PA[i][j] via 4 ds_write_b64;
// O = P.V (A=P b128 reads, B=V^T staged); row-sums via extra MFMA with B=ones.
// No js split -> no combine kernel; out written directly with residual.
__global__ __launch_bounds__(256, 2) void k_attn(
    const unsigned short* __restrict__ Qs, const unsigned short* __restrict__ Kb,
    const unsigned short* __restrict__ Vt, const unsigned short* __restrict__ mq,
    const float* __restrict__ x, float* __restrict__ out) {
    __shared__ __align__(16) unsigned short Ks[4096];     // [kk][64 j][32 d]
    __shared__ __align__(16) unsigned short Vs[4096];     // [jc][64 d][32 j]
    __shared__ __align__(16) unsigned short PA[4][16 * 72];  // per-wave P[i][j], stride 72
    int bid = blockIdx.x;
    int ig = bid >> 4, h = (bid >> 1) & 7, b = bid & 1;
    int tid = threadIdx.x, w = tid >> 6, l = tid & 63, q = l >> 4, cl = l & 15;
    int i0w = ig * 64 + w * 16;           // wave's 16-row base within batch b
    int ic = ig * 4 + w;

    // Q^T B-fragments, loop-invariant: lane needs Q[i0w+cl][h*64 + kk*32 + q*8 ..+7]
    bf16x8 qf0, qf1;
    {
        const unsigned short* qp = Qs + (size_t)(b * 2048 + i0w + cl) * 512 + h * 64 + q * 8;
        qf0 = *reinterpret_cast<const bf16x8*>(qp);
        qf1 = *reinterpret_cast<const bf16x8*>(qp + 32);
    }
    // ones B-fragment for MFMA row-sum
    bf16x8 ones;
#pragma unroll
    for (int i = 0; i < 8; i++) { unsigned short o1 = 0x3F80; __builtin_memcpy(((unsigned short*)&ones) + i, &o1, 2); }

    f32x4 O[4];      // O[nt]: row i=q*4+r, col d=16nt+cl
    f32x4 Osum;      // row-sums (every col identical)
#pragma unroll
    for (int nt = 0; nt < 4; nt++)
#pragma unroll
        for (int r = 0; r < 4; r++) O[nt][r] = 0.f;
#pragma unroll
    for (int r = 0; r < 4; r++) Osum[r] = 0.f;

    const unsigned short* Kh = Kb + (size_t)b * 2048 * 512 + h * 64;
    const unsigned short* Vh = Vt + ((size_t)(b * 8 + h) * 64) * 2048;
    const unsigned short* mb = mq + (size_t)(b * 128 + ic) * 32768 + l * 16;
    unsigned short* pw = &PA[w][0];
    int lrow = l >> 2, lch = (l & 3) * 8;

    for (int t = 0; t < 32; t++) {
        int jb = t * 64;
        // stage K tile [64 j x 64 d] and V^T tile [64 d x 64 j]; wave stages chunks c=w*2, w*2+1
#pragma unroll
        for (int e = 0; e < 2; e++) {
            int c = w * 2 + e, kk = c >> 2, r16 = (c & 3) * 16;
            GLDS16(Kh + (size_t)(jb + r16 + lrow) * 512 + kk * 32 + lch, Ks + kk * 2048 + r16 * 32);
            GLDS16(Vh + (size_t)(r16 + lrow) * 2048 + jb + kk * 32 + lch, Vs + kk * 2048 + r16 * 32);
        }
        // m fragments (global, transposed perm): 16 bf16 for (mt,r) pairs
        u16x8 mh0 = *reinterpret_cast<const u16x8*>(mb + (size_t)t * 1024);
        u16x8 mh1 = *reinterpret_cast<const u16x8*>(mb + (size_t)t * 1024 + 8);
        __syncthreads();   // staging complete (drains vmcnt)
        // S^T = K.Q^T: tile mt covers j_local [16mt,16mt+16); accumulate over d (kk chunks)
        f32x4 S[4];
#pragma unroll
        for (int mt = 0; mt < 4; mt++) {
#pragma unroll
            for (int r = 0; r < 4; r++) S[mt][r] = 0.f;
            bf16x8 kf0 = *reinterpret_cast<const bf16x8*>(Ks + (16 * mt + cl) * 32 + q * 8);
            bf16x8 kf1 = *reinterpret_cast<const bf16x8*>(Ks + 2048 + (16 * mt + cl) * 32 + q * 8);
            S[mt] = __builtin_amdgcn_mfma_f32_16x16x32_bf16(kf0, qf0, S[mt], 0, 0, 0);
            S[mt] = __builtin_amdgcn_mfma_f32_16x16x32_bf16(kf1, qf1, S[mt], 0, 0, 0);
        }
        // p = exp2(S^T)*m; pack 4 consecutive j (quad rows) -> one ds_write_b64 per mt
#pragma unroll
        for (int mt = 0; mt < 4; mt++) {
            float p0 = fexp2(S[mt][0]) * bu2f((mt < 2) ? mh0[mt * 4 + 0] : mh1[(mt - 2) * 4 + 0]);
            float p1 = fexp2(S[mt][1]) * bu2f((mt < 2) ? mh0[mt * 4 + 1] : mh1[(mt - 2) * 4 + 1]);
            float p2 = fexp2(S[mt][2]) * bu2f((mt < 2) ? mh0[mt * 4 + 2] : mh1[(mt - 2) * 4 + 2]);
            float p3 = fexp2(S[mt][3]) * bu2f((mt < 2) ? mh0[mt * 4 + 3] : mh1[(mt - 2) * 4 + 3]);
            ushort4 o;
            o.x = f2bu(p0); o.y = f2bu(p1); o.z = f2bu(p2); o.w = f2bu(p3);
            // PA[i=cl][j = 16mt + q*4 + 0..3]
            *reinterpret_cast<ushort4*>(pw + cl * 72 + 16 * mt + q * 4) = o;
        }
        // O = P.V: A = P (wave-local LDS, b128), B = V^T staged; +ones MFMA for row sums
#pragma unroll
        for (int jc = 0; jc < 2; jc++) {
            bf16x8 pf = *reinterpret_cast<const bf16x8*>(pw + cl * 72 + jc * 32 + q * 8);
#pragma unroll
            for (int nt = 0; nt < 4; nt++) {
                bf16x8 vf = *reinterpret_cast<const bf16x8*>(Vs + jc * 2048 + (16 * nt + cl) * 32 + q * 8);
                O[nt] = __builtin_amdgcn_mfma_f32_16x16x32_bf16(pf, vf, O[nt], 0, 0, 0);
            }
            Osum = __builtin_amdgcn_mfma_f32_16x16x32_bf16(pf, ones, Osum, 0, 0, 0);
        }
        __syncthreads();   // all waves done with Ks/Vs before next staging
    }

    // epilogue: normalize + residual; lane (q,cl) holds rows i=q*4+r, cols d=16nt+cl
#pragma unroll
    for (int r = 0; r < 4; r++) {
        float inv = 1.0f / Osum[r];
        size_t base = (size_t)(b * 2048 + i0w + q * 4 + r) * 512 + h * 64;
#pragma unroll
        for (int nt = 0; nt < 4; nt++) {
            size_t idx = base + 16 * nt + cl;
            out[idx] = O[nt][r] * inv + x[idx];
        }
    }
}

extern "C" void kernel_launch(void* const* d_in, const int* in_sizes, int n_in,
                              void* d_out, int out_size, void* d_ws, size_t ws_size,
                              hipStream_t stream) {
    const float* x   = (const float*)d_in[0];
    const float* adj = (const float*)d_in[1];
    const float* Wq  = (const float*)d_in[2];
    const float* bq  = (const float*)d_in[3];
    const float* Wk  = (const float*)d_in[4];
    const float* bk  = (const float*)d_in[5];
    const float* Wv  = (const float*)d_in[6];
    const float* bv  = (const float*)d_in[7];
    const float* wg  = (const float*)d_in[8];
    // d_in[9] (b_g) unused: row-constant bias cancels in softmax
    float* out = (float*)d_out;
    char* ws = (char*)d_ws;
    unsigned short* Qs = (unsigned short*)(ws + OFF_QS);
    unsigned short* Kb = (unsigned short*)(ws + OFF_KB);
    unsigned short* Vt = (unsigned short*)(ws + OFF_VT);
    float* cv2 = (float*)(ws + OFF_CV);
    unsigned short* xb = (unsigned short*)(ws + OFF_XB);
    unsigned short* wt = (unsigned short*)(ws + OFF_WT);
    unsigned short* mqp = (unsigned short*)(ws + OFF_MQ);

    k_prepwt<<<1216, 256, 0, stream>>>(x, wg, Wq, Wk, Wv, xb, cv2, wt);
    k_mid<<<8960, 256, 0, stream>>>(adj, cv2, mqp, xb, wt, bq, bk, bv, Qs, Kb, Vt);
    k_attn<<<512, 256, 0, stream>>>(Qs, Kb, Vt, mqp, x, out);
}

// Round 7
// 159.140 us; speedup vs baseline: 1.6831x; 1.0038x over previous
//
#include <hip/hip_runtime.h>
#include <hip/hip_bf16.h>

// Problem constants: B=2, N=2048, D=512, H=8, hd=64
typedef __bf16 bf16x8 __attribute__((ext_vector_type(8)));
typedef float f32x4 __attribute__((ext_vector_type(4)));
typedef unsigned short u16x8 __attribute__((ext_vector_type(8)));

#define LOG2E 1.44269504f

__device__ __forceinline__ unsigned short f2bu(float f) {
    __hip_bfloat16 h = __float2bfloat16(f);
    unsigned short u;
    __builtin_memcpy(&u, &h, 2);
    return u;
}

__device__ __forceinline__ float fexp2(float x) {
#if __has_builtin(__builtin_amdgcn_exp2f)
    return __builtin_amdgcn_exp2f(x);
#else
    return __expf(x * 0.69314718f);
#endif
}

__device__ __forceinline__ float bu2f(unsigned short u) {
    unsigned int v = ((unsigned int)u) << 16;
    float f;
    __builtin_memcpy(&f, &v, 4);
    return f;
}

// async global->LDS, 16B per lane. LDS base must be wave-uniform; HW appends lane*16.
#define GLDS16(gp, lp) __builtin_amdgcn_global_load_lds( \
    (const __attribute__((address_space(1))) unsigned int*)(gp), \
    (__attribute__((address_space(3))) unsigned int*)(lp), 16, 0, 0)

// ---- workspace layout (bytes) ----
#define OFF_QS  0u                          // Q*(0.125*log2e) bf16  4 MB
#define OFF_KB  4194304u                    // K bf16                4 MB
#define OFF_VT  8388608u                    // V^T [b,h,d,n] bf16    4 MB
#define OFF_CV  12582912u                   // cv2[b,n] f32 = 2^((c-8)*log2e)  16 KB
#define OFF_XB  12599296u                   // x bf16                4 MB
#define OFF_WT  16793600u                   // W^T bf16              1.5 MB
#define OFF_MQ  18366464u                   // m transposed-perm bf16 16.78 MB
#define OFF_PO  35143680u                   // partial O bf16, 4096 chunks x 1024  8.39 MB
#define OFF_PL  43532288u                   // partial lsum f32, 4096 chunks x 16  256 KB

// ---------------- prep (merged): x->bf16 + cv2, and Wt[n][k] = bf16(W[k][n]) ----------------
__global__ void k_prepwt(const float* __restrict__ x, const float* __restrict__ wg,
                         const float* __restrict__ w0, const float* __restrict__ w1,
                         const float* __restrict__ w2,
                         unsigned short* __restrict__ xb, float* __restrict__ cv2,
                         unsigned short* __restrict__ wt) {
    if (blockIdx.x < 1024) {
        int row = blockIdx.x * 4 + (threadIdx.x >> 6);   // 4096 rows
        int l = threadIdx.x & 63;
        const float4* xr = reinterpret_cast<const float4*>(x + (size_t)row * 512);
        float4 a = xr[l * 2], b2 = xr[l * 2 + 1];
        ushort4 o0, o1;
        o0.x = f2bu(a.x);  o0.y = f2bu(a.y);  o0.z = f2bu(a.z);  o0.w = f2bu(a.w);
        o1.x = f2bu(b2.x); o1.y = f2bu(b2.y); o1.z = f2bu(b2.z); o1.w = f2bu(b2.w);
        ushort4* dst = reinterpret_cast<ushort4*>(xb + (size_t)row * 512);
        dst[l * 2] = o0; dst[l * 2 + 1] = o1;
        const float4* wr = reinterpret_cast<const float4*>(wg + 512);
        float4 g0 = wr[l * 2], g1 = wr[l * 2 + 1];
        float s = a.x * g0.x + a.y * g0.y + a.z * g0.z + a.w * g0.w
                + b2.x * g1.x + b2.y * g1.y + b2.z * g1.z + b2.w * g1.w;
#pragma unroll
        for (int off = 32; off >= 1; off >>= 1) s += __shfl_xor(s, off, 64);
        if (l == 0) cv2[row] = fexp2((s - 8.0f) * LOG2E);
    } else {
        int bid2 = blockIdx.x - 1024;        // 192 blocks: z*64 + yy
        int z = bid2 >> 6, yy = bid2 & 63;
        int k0 = (yy >> 3) * 64, n0 = (yy & 7) * 64;
        const float* W = (z == 0) ? w0 : ((z == 1) ? w1 : w2);
        __shared__ float T[64][65];
        int c = threadIdx.x & 63, r0 = threadIdx.x >> 6;
#pragma unroll
        for (int i = 0; i < 16; i++) { int r = r0 + i * 4; T[r][c] = W[(k0 + r) * 512 + n0 + c]; }
        __syncthreads();
        unsigned short* Wt = wt + z * (512 * 512);
#pragma unroll
        for (int i = 0; i < 16; i++) { int a = r0 + i * 4; Wt[(n0 + a) * 512 + k0 + c] = f2bu(T[c][a]); }
    }
}

// ---------------- merged: adjp (transposed perm) + QKV GEMM ----------------
// adjp (blocks 0..8191): mq[((b*128+ic)*32+jt)*1024 + l*16 + mt*4 + r]
//   = bf16((adj[b][ic*16+cl][j] + eps) * cv2[b][j]),  j = jt*64 + 16*mt + q*4 + r, l=q*16+cl.
// gemm (blocks 8192..8959): 64x128 tile QKV projection; z==2 writes V^T directly.
__global__ __launch_bounds__(256) void k_mid(
    const float* __restrict__ adj, const float* __restrict__ cv2,
    unsigned short* __restrict__ mq,
    const unsigned short* __restrict__ xb, const unsigned short* __restrict__ wt,
    const float* __restrict__ bq, const float* __restrict__ bk, const float* __restrict__ bv,
    unsigned short* __restrict__ Qs, unsigned short* __restrict__ Kb,
    unsigned short* __restrict__ Vt) {
    if (blockIdx.x < 8192) {
        int blk = blockIdx.x;              // bic*32 + jt
        int bic = blk >> 5, jt = blk & 31;
        int b = bic >> 7, ic = bic & 127;
        int t = threadIdx.x;               // t = l*4 + mt
        int l = t >> 2, mt = t & 3, q = l >> 4, cl = l & 15;
        int j0 = jt * 64 + 16 * mt + q * 4;
        const float4 av = *reinterpret_cast<const float4*>(
            adj + ((size_t)(b * 2048 + ic * 16 + cl)) * 2048 + j0);
        const float4 cv = *reinterpret_cast<const float4*>(cv2 + b * 2048 + j0);
        ushort4 o;
        o.x = f2bu((av.x + 1e-9f) * cv.x);
        o.y = f2bu((av.y + 1e-9f) * cv.y);
        o.z = f2bu((av.z + 1e-9f) * cv.z);
        o.w = f2bu((av.w + 1e-9f) * cv.w);
        *reinterpret_cast<ushort4*>(mq + (size_t)bic * 32768 + jt * 1024 + l * 16 + mt * 4) = o;
        return;
    }
    int gid = blockIdx.x - 8192;           // 768: x(64) y(4) z(3)
    int bx = gid & 63, by = (gid >> 6) & 3, z = gid >> 8;
    __shared__ __align__(16) unsigned short As[64 * 32];
    __shared__ __align__(16) unsigned short Bs[128 * 32];
    const unsigned short* Wt = wt + z * (512 * 512);
    const float* bias = (z == 0) ? bq : ((z == 1) ? bk : bv);
    float scale = (z == 0) ? (0.125f * LOG2E) : 1.0f;   // Q pre-scaled by log2e/sqrt(64)
    int m0 = bx * 64, n0 = by * 128;
    int tid = threadIdx.x, w = tid >> 6, l = tid & 63;
    int q = l >> 4, cl = l & 15;
    f32x4 acc[8];
#pragma unroll
    for (int nt = 0; nt < 8; nt++)
#pragma unroll
        for (int r = 0; r < 4; r++) acc[nt][r] = 0.f;
    int arow = l >> 2, ach = (l & 3) * 8;
    for (int k0 = 0; k0 < 512; k0 += 32) {
        GLDS16(xb + (size_t)(m0 + w * 16 + arow) * 512 + k0 + ach, As + w * 512);
#pragma unroll
        for (int e = 0; e < 2; e++)
            GLDS16(Wt + (size_t)(n0 + w * 32 + e * 16 + arow) * 512 + k0 + ach, Bs + w * 1024 + e * 512);
        __syncthreads();
        bf16x8 af = *reinterpret_cast<const bf16x8*>(As + (w * 16 + cl) * 32 + q * 8);
#pragma unroll
        for (int nt = 0; nt < 8; nt++) {
            bf16x8 bf = *reinterpret_cast<const bf16x8*>(Bs + (nt * 16 + cl) * 32 + q * 8);
            acc[nt] = __builtin_amdgcn_mfma_f32_16x16x32_bf16(af, bf, acc[nt], 0, 0, 0);
        }
        __syncthreads();
    }
    if (z == 2) {
        int n_ = (m0 + w * 16 + q * 4) & 2047;
        int b_ = (m0 + w * 16) >> 11;
#pragma unroll
        for (int nt = 0; nt < 8; nt++) {
            int col = n0 + nt * 16 + cl;
            int h_ = col >> 6, d_ = col & 63;
            float bv_ = bias[col];
            ushort4 o;
            o.x = f2bu(acc[nt][0] + bv_); o.y = f2bu(acc[nt][1] + bv_);
            o.z = f2bu(acc[nt][2] + bv_); o.w = f2bu(acc[nt][3] + bv_);
            *reinterpret_cast<ushort4*>(Vt + ((size_t)((b_ * 8 + h_) * 64 + d_)) * 2048 + n_) = o;
        }
    } else {
        unsigned short* Cout = (z == 0) ? Qs : Kb;
#pragma unroll
        for (int nt = 0; nt < 8; nt++) {
            int col = n0 + nt * 16 + cl;
            float bv_ = bias[col];
#pragma unroll
            for (int r = 0; r < 4; r++) {
                int row = m0 + w * 16 + q * 4 + r;
                Cout[(size_t)row * 512 + col] = f2bu((acc[nt][r] + bv_) * scale);
            }
        }
    }
}

// ---------------- flash attention: transposed-S, double-buffered LDS, 32 rows/wave ----------------
// 512 blocks x 256 thr. bid = h*64 + b*32 + ig*2 + js (h-siblings share XCD for mq L2 reuse).
// Wave w: rows [ig*128 + w*32, +32) as 2 chunks rc; j-range [js*1024,+1024) = 16 tiles of 64.
// Per iter: ONE barrier; stage(t+1) into buf^1 right after it (vmcnt drained a full iter later);
// m-multiplier register-prefetched one iter ahead; V fragments held in regs across rc.
// S^T = K.Q^T; p = exp2(S^T)*m; P->PA (4x ds_write_b64/rc); O = P.V; row sums via ones-MFMA.
__global__ __launch_bounds__(256, 2) void k_attn(
    const unsigned short* __restrict__ Qs, const unsigned short* __restrict__ Kb,
    const unsigned short* __restrict__ Vt, const unsigned short* __restrict__ mq,
    unsigned short* __restrict__ PO, float* __restrict__ PL) {
    __shared__ __align__(16) unsigned short Ks[2][4096];   // [buf][kk][64 j][32 d]
    __shared__ __align__(16) unsigned short Vs[2][4096];   // [buf][jc][64 d][32 j]
    __shared__ __align__(16) unsigned short PA[4][16 * 72];  // per-wave P[i][j], stride 72
    int bid = blockIdx.x;
    int h = bid >> 6, s = bid & 63, b = s >> 5, ig = (s >> 1) & 15, js = s & 1;
    int tid = threadIdx.x, w = tid >> 6, l = tid & 63, q = l >> 4, cl = l & 15;
    int bh = b * 8 + h;
    int ic0 = ig * 8 + w * 2;

    // Q^T B-fragments for 2 row-chunks, loop-invariant
    bf16x8 qf[2][2];
#pragma unroll
    for (int rc = 0; rc < 2; rc++) {
        const unsigned short* qp = Qs + (size_t)(b * 2048 + ig * 128 + w * 32 + rc * 16 + cl) * 512 + h * 64 + q * 8;
        qf[rc][0] = *reinterpret_cast<const bf16x8*>(qp);
        qf[rc][1] = *reinterpret_cast<const bf16x8*>(qp + 32);
    }
    bf16x8 ones;
#pragma unroll
    for (int i = 0; i < 8; i++) { unsigned short o1 = 0x3F80; __builtin_memcpy(((unsigned short*)&ones) + i, &o1, 2); }

    f32x4 O[2][4];
    f32x4 Osum[2];
#pragma unroll
    for (int rc = 0; rc < 2; rc++) {
#pragma unroll
        for (int nt = 0; nt < 4; nt++)
#pragma unroll
            for (int r = 0; r < 4; r++) O[rc][nt][r] = 0.f;
#pragma unroll
        for (int r = 0; r < 4; r++) Osum[rc][r] = 0.f;
    }

    const unsigned short* Kh = Kb + (size_t)b * 2048 * 512 + h * 64;
    const unsigned short* Vh = Vt + ((size_t)bh * 64) * 2048;
    const unsigned short* mb0 = mq + (size_t)(b * 128 + ic0) * 32768 + l * 16 + (size_t)(js * 16) * 1024;
    const unsigned short* mb1 = mb0 + 32768;
    unsigned short* pw = &PA[w][0];
    int lrow = l >> 2, lch = (l & 3) * 8;
    int jb0 = js * 1024;

    // stage tile 0 into buf 0
    {
        int jb = jb0;
#pragma unroll
        for (int e = 0; e < 2; e++) {
            int c = w * 2 + e, kk = c >> 2, r16 = (c & 3) * 16;
            GLDS16(Kh + (size_t)(jb + r16 + lrow) * 512 + kk * 32 + lch, &Ks[0][kk * 2048 + r16 * 32]);
            GLDS16(Vh + (size_t)(r16 + lrow) * 2048 + jb + kk * 32 + lch, &Vs[0][kk * 2048 + r16 * 32]);
        }
    }
    // prefetch m for tile 0
    u16x8 mn[2][2];
    mn[0][0] = *reinterpret_cast<const u16x8*>(mb0);
    mn[0][1] = *reinterpret_cast<const u16x8*>(mb0 + 8);
    mn[1][0] = *reinterpret_cast<const u16x8*>(mb1);
    mn[1][1] = *reinterpret_cast<const u16x8*>(mb1 + 8);

    for (int t = 0; t < 16; t++) {
        int bufi = t & 1;
        __syncthreads();   // tile t staged (vmcnt drained pre-barrier; issued a full iter ago)
        if (t < 15) {
            int jb = jb0 + (t + 1) * 64;
#pragma unroll
            for (int e = 0; e < 2; e++) {
                int c = w * 2 + e, kk = c >> 2, r16 = (c & 3) * 16;
                GLDS16(Kh + (size_t)(jb + r16 + lrow) * 512 + kk * 32 + lch, &Ks[bufi ^ 1][kk * 2048 + r16 * 32]);
                GLDS16(Vh + (size_t)(r16 + lrow) * 2048 + jb + kk * 32 + lch, &Vs[bufi ^ 1][kk * 2048 + r16 * 32]);
            }
        }
        u16x8 mc[2][2];
        mc[0][0] = mn[0][0]; mc[0][1] = mn[0][1]; mc[1][0] = mn[1][0]; mc[1][1] = mn[1][1];
        if (t < 15) {
            size_t off = (size_t)(t + 1) * 1024;
            mn[0][0] = *reinterpret_cast<const u16x8*>(mb0 + off);
            mn[0][1] = *reinterpret_cast<const u16x8*>(mb0 + off + 8);
            mn[1][0] = *reinterpret_cast<const u16x8*>(mb1 + off);
            mn[1][1] = *reinterpret_cast<const u16x8*>(mb1 + off + 8);
        }
        // V fragments into regs (reused across rc)
        bf16x8 vf[2][4];
#pragma unroll
        for (int jc = 0; jc < 2; jc++)
#pragma unroll
            for (int nt = 0; nt < 4; nt++)
                vf[jc][nt] = *reinterpret_cast<const bf16x8*>(&Vs[bufi][jc * 2048 + (16 * nt + cl) * 32 + q * 8]);
        // S^T = K.Q^T for both rc (K fragments read once)
        f32x4 S[2][4];
#pragma unroll
        for (int rc = 0; rc < 2; rc++)
#pragma unroll
            for (int mt = 0; mt < 4; mt++)
#pragma unroll
                for (int r = 0; r < 4; r++) S[rc][mt][r] = 0.f;
#pragma unroll
        for (int mt = 0; mt < 4; mt++) {
            bf16x8 kf0 = *reinterpret_cast<const bf16x8*>(&Ks[bufi][(16 * mt + cl) * 32 + q * 8]);
            bf16x8 kf1 = *reinterpret_cast<const bf16x8*>(&Ks[bufi][2048 + (16 * mt + cl) * 32 + q * 8]);
#pragma unroll
            for (int rc = 0; rc < 2; rc++) {
                S[rc][mt] = __builtin_amdgcn_mfma_f32_16x16x32_bf16(kf0, qf[rc][0], S[rc][mt], 0, 0, 0);
                S[rc][mt] = __builtin_amdgcn_mfma_f32_16x16x32_bf16(kf1, qf[rc][1], S[rc][mt], 0, 0, 0);
            }
        }
        // per rc: p = exp2(S^T)*m -> PA (b64 writes) -> PV MFMA
#pragma unroll
        for (int rc = 0; rc < 2; rc++) {
#pragma unroll
            for (int mt = 0; mt < 4; mt++) {
                float p0 = fexp2(S[rc][mt][0]) * bu2f((mt < 2) ? mc[rc][0][mt * 4 + 0] : mc[rc][1][(mt - 2) * 4 + 0]);
                float p1 = fexp2(S[rc][mt][1]) * bu2f((mt < 2) ? mc[rc][0][mt * 4 + 1] : mc[rc][1][(mt - 2) * 4 + 1]);
                float p2 = fexp2(S[rc][mt][2]) * bu2f((mt < 2) ? mc[rc][0][mt * 4 + 2] : mc[rc][1][(mt - 2) * 4 + 2]);
                float p3 = fexp2(S[rc][mt][3]) * bu2f((mt < 2) ? mc[rc][0][mt * 4 + 3] : mc[rc][1][(mt - 2) * 4 + 3]);
                ushort4 o;
                o.x = f2bu(p0); o.y = f2bu(p1); o.z = f2bu(p2); o.w = f2bu(p3);
                *reinterpret_cast<ushort4*>(pw + cl * 72 + 16 * mt + q * 4) = o;
            }
#pragma unroll
            for (int jc = 0; jc < 2; jc++) {
                bf16x8 pf = *reinterpret_cast<const bf16x8*>(pw + cl * 72 + jc * 32 + q * 8);
#pragma unroll
                for (int nt = 0; nt < 4; nt++)
                    O[rc][nt] = __builtin_amdgcn_mfma_f32_16x16x32_bf16(pf, vf[jc][nt], O[rc][nt], 0, 0, 0);
                Osum[rc] = __builtin_amdgcn_mfma_f32_16x16x32_bf16(pf, ones, Osum[rc], 0, 0, 0);
            }
        }
    }

    // epilogue: write bf16 partial O (lane-packed) + row sums
#pragma unroll
    for (int rc = 0; rc < 2; rc++) {
        size_t chunk = ((size_t)(bh * 128 + ic0 + rc)) * 2 + js;
        unsigned short* po = PO + chunk * 1024 + l * 16;
#pragma unroll
        for (int r = 0; r < 4; r++) {
            ushort4 o;
            o.x = f2bu(O[rc][0][r]); o.y = f2bu(O[rc][1][r]);
            o.z = f2bu(O[rc][2][r]); o.w = f2bu(O[rc][3][r]);
            *reinterpret_cast<ushort4*>(po + r * 4) = o;
        }
        if (cl == 0) {
#pragma unroll
            for (int r = 0; r < 4; r++)
                PL[chunk * 16 + q * 4 + r] = Osum[rc][r];
        }
    }
}

// ---------------- combine j-halves, normalize, residual ----------------
// 512 blocks (bh*32 + t64) x 256 thr; each block 4 row-chunks (64 rows).
__global__ void k_comb(const unsigned short* __restrict__ PO, const float* __restrict__ PL,
                       const float* __restrict__ x, float* __restrict__ out) {
    int blk = blockIdx.x;
    int t64 = blk & 31, bh = blk >> 5;
    int b = bh >> 3, h = bh & 7;
    int t = threadIdx.x;               // t = l*4 + r
    int l = t >> 2, r = t & 3, q = l >> 4, cl = l & 15;
#pragma unroll
    for (int w = 0; w < 4; w++) {
        int ic = t64 * 4 + w;
        size_t c0 = ((size_t)(bh * 128 + ic)) * 2;
        ushort4 a = *reinterpret_cast<const ushort4*>(PO + c0 * 1024 + t * 4);
        ushort4 c = *reinterpret_cast<const ushort4*>(PO + (c0 + 1) * 1024 + t * 4);
        float inv = 1.0f / (PL[c0 * 16 + q * 4 + r] + PL[c0 * 16 + 16 + q * 4 + r]);
        size_t gro = (size_t)(b * 2048 + ic * 16 + q * 4 + r) * 512 + h * 64;
        out[gro + 0 * 16 + cl] = (bu2f(a.x) + bu2f(c.x)) * inv + x[gro + 0 * 16 + cl];
        out[gro + 1 * 16 + cl] = (bu2f(a.y) + bu2f(c.y)) * inv + x[gro + 1 * 16 + cl];
        out[gro + 2 * 16 + cl] = (bu2f(a.z) + bu2f(c.z)) * inv + x[gro + 2 * 16 + cl];
        out[gro + 3 * 16 + cl] = (bu2f(a.w) + bu2f(c.w)) * inv + x[gro + 3 * 16 + cl];
    }
}

extern "C" void kernel_launch(void* const* d_in, const int* in_sizes, int n_in,
                              void* d_out, int out_size, void* d_ws, size_t ws_size,
                              hipStream_t stream) {
    const float* x   = (const float*)d_in[0];
    const float* adj = (const float*)d_in[1];
    const float* Wq  = (const float*)d_in[2];
    const float* bq  = (const float*)d_in[3];
    const float* Wk  = (const float*)d_in[4];
    const float* bk  = (const float*)d_in[5];
    const float* Wv  = (const float*)d_in[6];
    const float* bv  = (const float*)d_in[7];
    const float* wg  = (const float*)d_in[8];
    // d_in[9] (b_g) unused: row-constant bias cancels in softmax
    float* out = (float*)d_out;
    char* ws = (char*)d_ws;
    unsigned short* Qs = (unsigned short*)(ws + OFF_QS);
    unsigned short* Kb = (unsigned short*)(ws + OFF_KB);
    unsigned short* Vt = (unsigned short*)(ws + OFF_VT);
    float* cv2 = (float*)(ws + OFF_CV);
    unsigned short* xb = (unsigned short*)(ws + OFF_XB);
    unsigned short* wt = (unsigned short*)(ws + OFF_WT);
    unsigned short* mqp = (unsigned short*)(ws + OFF_MQ);
    unsigned short* PO = (unsigned short*)(ws + OFF_PO);
    float* PL = (float*)(ws + OFF_PL);

    k_prepwt<<<1216, 256, 0, stream>>>(x, wg, Wq, Wk, Wv, xb, cv2, wt);
    k_mid<<<8960, 256, 0, stream>>>(adj, cv2, mqp, xb, wt, bq, bk, bv, Qs, Kb, Vt);
    k_attn<<<512, 256, 0, stream>>>(Qs, Kb, Vt, mqp, PO, PL);
    k_comb<<<512, 256, 0, stream>>>(PO, PL, x, out);
}

// Round 9
// 156.493 us; speedup vs baseline: 1.7115x; 1.0169x over previous
//
#include <hip/hip_runtime.h>
#include <hip/hip_bf16.h>

// Problem constants: B=2, N=2048, D=512, H=8, hd=64
typedef __bf16 bf16x8 __attribute__((ext_vector_type(8)));
typedef float f32x4 __attribute__((ext_vector_type(4)));
typedef unsigned short u16x8 __attribute__((ext_vector_type(8)));

#define LOG2E 1.44269504f

__device__ __forceinline__ unsigned short f2bu(float f) {
    __hip_bfloat16 h = __float2bfloat16(f);
    unsigned short u;
    __builtin_memcpy(&u, &h, 2);
    return u;
}

__device__ __forceinline__ float fexp2(float x) {
#if __has_builtin(__builtin_amdgcn_exp2f)
    return __builtin_amdgcn_exp2f(x);
#else
    return __expf(x * 0.69314718f);
#endif
}

__device__ __forceinline__ float bu2f(unsigned short u) {
    unsigned int v = ((unsigned int)u) << 16;
    float f;
    __builtin_memcpy(&f, &v, 4);
    return f;
}

// async global->LDS, 16B per lane. LDS base must be wave-uniform; HW appends lane*16.
#define GLDS16(gp, lp) __builtin_amdgcn_global_load_lds( \
    (const __attribute__((address_space(1))) unsigned int*)(gp), \
    (__attribute__((address_space(3))) unsigned int*)(lp), 16, 0, 0)

// ---- workspace layout (bytes) ----
#define OFF_QS  0u                          // Q*(0.125*log2e) bf16  4 MB
#define OFF_KB  4194304u                    // K bf16                4 MB
#define OFF_VT  8388608u                    // V^T [b,h,d,n] bf16    4 MB
#define OFF_CV  12582912u                   // cv2[b,n] f32 = 2^((c-8)*log2e)  16 KB
#define OFF_XB  12599296u                   // x bf16                4 MB
#define OFF_WT  16793600u                   // W^T bf16              1.5 MB
#define OFF_MQ  18366464u                   // m transposed-perm bf16 16.78 MB
#define OFF_PO  35143680u                   // partial O bf16, 8192 chunks x 1024  16.78 MB
#define OFF_PL  51920896u                   // partial lsum f32, 8192 chunks x 16  512 KB

// ---------------- prep (merged): x->bf16 + cv2, and Wt[n][k] = bf16(W[k][n]) ----------------
__global__ void k_prepwt(const float* __restrict__ x, const float* __restrict__ wg,
                         const float* __restrict__ w0, const float* __restrict__ w1,
                         const float* __restrict__ w2,
                         unsigned short* __restrict__ xb, float* __restrict__ cv2,
                         unsigned short* __restrict__ wt) {
    if (blockIdx.x < 1024) {
        int row = blockIdx.x * 4 + (threadIdx.x >> 6);   // 4096 rows
        int l = threadIdx.x & 63;
        const float4* xr = reinterpret_cast<const float4*>(x + (size_t)row * 512);
        float4 a = xr[l * 2], b2 = xr[l * 2 + 1];
        ushort4 o0, o1;
        o0.x = f2bu(a.x);  o0.y = f2bu(a.y);  o0.z = f2bu(a.z);  o0.w = f2bu(a.w);
        o1.x = f2bu(b2.x); o1.y = f2bu(b2.y); o1.z = f2bu(b2.z); o1.w = f2bu(b2.w);
        ushort4* dst = reinterpret_cast<ushort4*>(xb + (size_t)row * 512);
        dst[l * 2] = o0; dst[l * 2 + 1] = o1;
        const float4* wr = reinterpret_cast<const float4*>(wg + 512);
        float4 g0 = wr[l * 2], g1 = wr[l * 2 + 1];
        float s = a.x * g0.x + a.y * g0.y + a.z * g0.z + a.w * g0.w
                + b2.x * g1.x + b2.y * g1.y + b2.z * g1.z + b2.w * g1.w;
#pragma unroll
        for (int off = 32; off >= 1; off >>= 1) s += __shfl_xor(s, off, 64);
        if (l == 0) cv2[row] = fexp2((s - 8.0f) * LOG2E);
    } else {
        int bid2 = blockIdx.x - 1024;        // 192 blocks: z*64 + yy
        int z = bid2 >> 6, yy = bid2 & 63;
        int k0 = (yy >> 3) * 64, n0 = (yy & 7) * 64;
        const float* W = (z == 0) ? w0 : ((z == 1) ? w1 : w2);
        __shared__ float T[64][65];
        int c = threadIdx.x & 63, r0 = threadIdx.x >> 6;
#pragma unroll
        for (int i = 0; i < 16; i++) { int r = r0 + i * 4; T[r][c] = W[(k0 + r) * 512 + n0 + c]; }
        __syncthreads();
        unsigned short* Wt = wt + z * (512 * 512);
#pragma unroll
        for (int i = 0; i < 16; i++) { int a = r0 + i * 4; Wt[(n0 + a) * 512 + k0 + c] = f2bu(T[c][a]); }
    }
}

// ---------------- merged: adjp (transposed perm) + QKV GEMM ----------------
// adjp (blocks 0..8191): mq[((b*128+ic)*32+jt)*1024 + l*16 + mt*4 + r]
//   = bf16((adj[b][ic*16+cl][j] + eps) * cv2[b][j]),  j = jt*64 + 16*mt + q*4 + r, l=q*16+cl.
// gemm (blocks 8192..8959): 64x128 tile QKV projection; z==2 writes V^T directly.
__global__ __launch_bounds__(256) void k_mid(
    const float* __restrict__ adj, const float* __restrict__ cv2,
    unsigned short* __restrict__ mq,
    const unsigned short* __restrict__ xb, const unsigned short* __restrict__ wt,
    const float* __restrict__ bq, const float* __restrict__ bk, const float* __restrict__ bv,
    unsigned short* __restrict__ Qs, unsigned short* __restrict__ Kb,
    unsigned short* __restrict__ Vt) {
    if (blockIdx.x < 8192) {
        int blk = blockIdx.x;              // bic*32 + jt
        int bic = blk >> 5, jt = blk & 31;
        int b = bic >> 7, ic = bic & 127;
        int t = threadIdx.x;               // t = l*4 + mt
        int l = t >> 2, mt = t & 3, q = l >> 4, cl = l & 15;
        int j0 = jt * 64 + 16 * mt + q * 4;
        const float4 av = *reinterpret_cast<const float4*>(
            adj + ((size_t)(b * 2048 + ic * 16 + cl)) * 2048 + j0);
        const float4 cv = *reinterpret_cast<const float4*>(cv2 + b * 2048 + j0);
        ushort4 o;
        o.x = f2bu((av.x + 1e-9f) * cv.x);
        o.y = f2bu((av.y + 1e-9f) * cv.y);
        o.z = f2bu((av.z + 1e-9f) * cv.z);
        o.w = f2bu((av.w + 1e-9f) * cv.w);
        *reinterpret_cast<ushort4*>(mq + (size_t)bic * 32768 + jt * 1024 + l * 16 + mt * 4) = o;
        return;
    }
    int gid = blockIdx.x - 8192;           // 768: x(64) y(4) z(3)
    int bx = gid & 63, by = (gid >> 6) & 3, z = gid >> 8;
    __shared__ __align__(16) unsigned short As[64 * 32];
    __shared__ __align__(16) unsigned short Bs[128 * 32];
    const unsigned short* Wt = wt + z * (512 * 512);
    const float* bias = (z == 0) ? bq : ((z == 1) ? bk : bv);
    float scale = (z == 0) ? (0.125f * LOG2E) : 1.0f;   // Q pre-scaled by log2e/sqrt(64)
    int m0 = bx * 64, n0 = by * 128;
    int tid = threadIdx.x, w = tid >> 6, l = tid & 63;
    int q = l >> 4, cl = l & 15;
    f32x4 acc[8];
#pragma unroll
    for (int nt = 0; nt < 8; nt++)
#pragma unroll
        for (int r = 0; r < 4; r++) acc[nt][r] = 0.f;
    int arow = l >> 2, ach = (l & 3) * 8;
    for (int k0 = 0; k0 < 512; k0 += 32) {
        GLDS16(xb + (size_t)(m0 + w * 16 + arow) * 512 + k0 + ach, As + w * 512);
#pragma unroll
        for (int e = 0; e < 2; e++)
            GLDS16(Wt + (size_t)(n0 + w * 32 + e * 16 + arow) * 512 + k0 + ach, Bs + w * 1024 + e * 512);
        __syncthreads();
        bf16x8 af = *reinterpret_cast<const bf16x8*>(As + (w * 16 + cl) * 32 + q * 8);
#pragma unroll
        for (int nt = 0; nt < 8; nt++) {
            bf16x8 bf = *reinterpret_cast<const bf16x8*>(Bs + (nt * 16 + cl) * 32 + q * 8);
            acc[nt] = __builtin_amdgcn_mfma_f32_16x16x32_bf16(af, bf, acc[nt], 0, 0, 0);
        }
        __syncthreads();
    }
    if (z == 2) {
        int n_ = (m0 + w * 16 + q * 4) & 2047;
        int b_ = (m0 + w * 16) >> 11;
#pragma unroll
        for (int nt = 0; nt < 8; nt++) {
            int col = n0 + nt * 16 + cl;
            int h_ = col >> 6, d_ = col & 63;
            float bv_ = bias[col];
            ushort4 o;
            o.x = f2bu(acc[nt][0] + bv_); o.y = f2bu(acc[nt][1] + bv_);
            o.z = f2bu(acc[nt][2] + bv_); o.w = f2bu(acc[nt][3] + bv_);
            *reinterpret_cast<ushort4*>(Vt + ((size_t)((b_ * 8 + h_) * 64 + d_)) * 2048 + n_) = o;
        }
    } else {
        unsigned short* Cout = (z == 0) ? Qs : Kb;
#pragma unroll
        for (int nt = 0; nt < 8; nt++) {
            int col = n0 + nt * 16 + cl;
            float bv_ = bias[col];
#pragma unroll
            for (int r = 0; r < 4; r++) {
                int row = m0 + w * 16 + q * 4 + r;
                Cout[(size_t)row * 512 + col] = f2bu((acc[nt][r] + bv_) * scale);
            }
        }
    }
}

// ---------------- flash attention: transposed-S, dbuf LDS, 32 rows/wave, j-quarters ----------------
// 1024 blocks x 256 thr, 3 blocks/CU (12 waves/CU). bid = h*128 + b*64 + ig*4 + js.
// Wave w: rows [ig*128 + w*32, +32) as 2 chunks rc; j-range [js*512,+512) = 8 tiles of 64.
// One barrier/iter; stage(t+1) into buf^1 after it. PA sized 32*72/wave: BOTH rc chunks live
// before PV reads them (r8 bug: 16*72 -> wave overlap + OOB -> NaN).
__global__ __launch_bounds__(256, 3) void k_attn(
    const unsigned short* __restrict__ Qs, const unsigned short* __restrict__ Kb,
    const unsigned short* __restrict__ Vt, const unsigned short* __restrict__ mq,
    unsigned short* __restrict__ PO, float* __restrict__ PL) {
    __shared__ __align__(16) unsigned short Ks[2][4096];   // [buf][kk][64 j][32 d]
    __shared__ __align__(16) unsigned short Vs[2][4096];   // [buf][jc][64 d][32 j]
    __shared__ __align__(16) unsigned short PA[4][32 * 72];  // per-wave P[i][j] (2 rc), stride 72
    int bid = blockIdx.x;
    int h = bid >> 7, b = (bid >> 6) & 1, ig = (bid >> 2) & 15, js = bid & 3;
    int tid = threadIdx.x, w = tid >> 6, l = tid & 63, q = l >> 4, cl = l & 15;
    int bh = b * 8 + h;
    int ic0 = ig * 8 + w * 2;

    // Q^T B-fragments for 2 row-chunks, loop-invariant
    bf16x8 qf[2][2];
#pragma unroll
    for (int rc = 0; rc < 2; rc++) {
        const unsigned short* qp = Qs + (size_t)(b * 2048 + ig * 128 + w * 32 + rc * 16 + cl) * 512 + h * 64 + q * 8;
        qf[rc][0] = *reinterpret_cast<const bf16x8*>(qp);
        qf[rc][1] = *reinterpret_cast<const bf16x8*>(qp + 32);
    }
    bf16x8 ones;
#pragma unroll
    for (int i = 0; i < 8; i++) { unsigned short o1 = 0x3F80; __builtin_memcpy(((unsigned short*)&ones) + i, &o1, 2); }

    f32x4 O[2][4];
    f32x4 Osum[2];
#pragma unroll
    for (int rc = 0; rc < 2; rc++) {
#pragma unroll
        for (int nt = 0; nt < 4; nt++)
#pragma unroll
            for (int r = 0; r < 4; r++) O[rc][nt][r] = 0.f;
#pragma unroll
        for (int r = 0; r < 4; r++) Osum[rc][r] = 0.f;
    }

    const unsigned short* Kh = Kb + (size_t)b * 2048 * 512 + h * 64;
    const unsigned short* Vh = Vt + ((size_t)bh * 64) * 2048;
    const unsigned short* mb0 = mq + (size_t)(b * 128 + ic0) * 32768 + l * 16 + (size_t)(js * 8) * 1024;
    const unsigned short* mb1 = mb0 + 32768;
    unsigned short* pw = &PA[w][0];
    int lrow = l >> 2, lch = (l & 3) * 8;
    int jb0 = js * 512;

    // stage tile 0 into buf 0
#pragma unroll
    for (int e = 0; e < 2; e++) {
        int c = w * 2 + e, kk = c >> 2, r16 = (c & 3) * 16;
        GLDS16(Kh + (size_t)(jb0 + r16 + lrow) * 512 + kk * 32 + lch, &Ks[0][kk * 2048 + r16 * 32]);
        GLDS16(Vh + (size_t)(r16 + lrow) * 2048 + jb0 + kk * 32 + lch, &Vs[0][kk * 2048 + r16 * 32]);
    }

    for (int t = 0; t < 8; t++) {
        int bufi = t & 1;
        __syncthreads();   // tile t staged (vmcnt drained pre-barrier; issued a full iter ago)
        if (t < 7) {
            int jb = jb0 + (t + 1) * 64;
#pragma unroll
            for (int e = 0; e < 2; e++) {
                int c = w * 2 + e, kk = c >> 2, r16 = (c & 3) * 16;
                GLDS16(Kh + (size_t)(jb + r16 + lrow) * 512 + kk * 32 + lch, &Ks[bufi ^ 1][kk * 2048 + r16 * 32]);
                GLDS16(Vh + (size_t)(r16 + lrow) * 2048 + jb + kk * 32 + lch, &Vs[bufi ^ 1][kk * 2048 + r16 * 32]);
            }
        }
        // m fragments for tile t (global; issued now, consumed after S+exp2)
        u16x8 mc[2][2];
        {
            size_t off = (size_t)t * 1024;
            mc[0][0] = *reinterpret_cast<const u16x8*>(mb0 + off);
            mc[0][1] = *reinterpret_cast<const u16x8*>(mb0 + off + 8);
            mc[1][0] = *reinterpret_cast<const u16x8*>(mb1 + off);
            mc[1][1] = *reinterpret_cast<const u16x8*>(mb1 + off + 8);
        }
        // S^T = K.Q^T for both rc (K fragments read once)
        f32x4 S[2][4];
#pragma unroll
        for (int rc = 0; rc < 2; rc++)
#pragma unroll
            for (int mt = 0; mt < 4; mt++)
#pragma unroll
                for (int r = 0; r < 4; r++) S[rc][mt][r] = 0.f;
#pragma unroll
        for (int mt = 0; mt < 4; mt++) {
            bf16x8 kf0 = *reinterpret_cast<const bf16x8*>(&Ks[bufi][(16 * mt + cl) * 32 + q * 8]);
            bf16x8 kf1 = *reinterpret_cast<const bf16x8*>(&Ks[bufi][2048 + (16 * mt + cl) * 32 + q * 8]);
#pragma unroll
            for (int rc = 0; rc < 2; rc++) {
                S[rc][mt] = __builtin_amdgcn_mfma_f32_16x16x32_bf16(kf0, qf[rc][0], S[rc][mt], 0, 0, 0);
                S[rc][mt] = __builtin_amdgcn_mfma_f32_16x16x32_bf16(kf1, qf[rc][1], S[rc][mt], 0, 0, 0);
            }
        }
        // per rc: p = exp2(S^T)*m -> PA (b64 writes); then PV with transient V fragments
#pragma unroll
        for (int rc = 0; rc < 2; rc++) {
#pragma unroll
            for (int mt = 0; mt < 4; mt++) {
                float p0 = fexp2(S[rc][mt][0]) * bu2f((mt < 2) ? mc[rc][0][mt * 4 + 0] : mc[rc][1][(mt - 2) * 4 + 0]);
                float p1 = fexp2(S[rc][mt][1]) * bu2f((mt < 2) ? mc[rc][0][mt * 4 + 1] : mc[rc][1][(mt - 2) * 4 + 1]);
                float p2 = fexp2(S[rc][mt][2]) * bu2f((mt < 2) ? mc[rc][0][mt * 4 + 2] : mc[rc][1][(mt - 2) * 4 + 2]);
                float p3 = fexp2(S[rc][mt][3]) * bu2f((mt < 2) ? mc[rc][0][mt * 4 + 3] : mc[rc][1][(mt - 2) * 4 + 3]);
                ushort4 o;
                o.x = f2bu(p0); o.y = f2bu(p1); o.z = f2bu(p2); o.w = f2bu(p3);
                *reinterpret_cast<ushort4*>(pw + rc * (16 * 72) + cl * 72 + 16 * mt + q * 4) = o;
            }
        }
        // O += P.V: per jc read both rc P-fragments, stream V fragments once
#pragma unroll
        for (int jc = 0; jc < 2; jc++) {
            bf16x8 pf0 = *reinterpret_cast<const bf16x8*>(pw + cl * 72 + jc * 32 + q * 8);
            bf16x8 pf1 = *reinterpret_cast<const bf16x8*>(pw + 16 * 72 + cl * 72 + jc * 32 + q * 8);
#pragma unroll
            for (int nt = 0; nt < 4; nt++) {
                bf16x8 vf = *reinterpret_cast<const bf16x8*>(&Vs[bufi][jc * 2048 + (16 * nt + cl) * 32 + q * 8]);
                O[0][nt] = __builtin_amdgcn_mfma_f32_16x16x32_bf16(pf0, vf, O[0][nt], 0, 0, 0);
                O[1][nt] = __builtin_amdgcn_mfma_f32_16x16x32_bf16(pf1, vf, O[1][nt], 0, 0, 0);
            }
            Osum[0] = __builtin_amdgcn_mfma_f32_16x16x32_bf16(pf0, ones, Osum[0], 0, 0, 0);
            Osum[1] = __builtin_amdgcn_mfma_f32_16x16x32_bf16(pf1, ones, Osum[1], 0, 0, 0);
        }
    }

    // epilogue: write bf16 partial O (lane-packed) + row sums
#pragma unroll
    for (int rc = 0; rc < 2; rc++) {
        size_t chunk = ((size_t)(bh * 128 + ic0 + rc)) * 4 + js;
        unsigned short* po = PO + chunk * 1024 + l * 16;
#pragma unroll
        for (int r = 0; r < 4; r++) {
            ushort4 o;
            o.x = f2bu(O[rc][0][r]); o.y = f2bu(O[rc][1][r]);
            o.z = f2bu(O[rc][2][r]); o.w = f2bu(O[rc][3][r]);
            *reinterpret_cast<ushort4*>(po + r * 4) = o;
        }
        if (cl == 0) {
#pragma unroll
            for (int r = 0; r < 4; r++)
                PL[chunk * 16 + q * 4 + r] = Osum[rc][r];
        }
    }
}

// ---------------- combine 4 j-quarters, normalize, residual ----------------
// 512 blocks (bh*32 + t64) x 256 thr; each block 4 row-chunks (64 rows).
__global__ void k_comb(const unsigned short* __restrict__ PO, const float* __restrict__ PL,
                       const float* __restrict__ x, float* __restrict__ out) {
    int blk = blockIdx.x;
    int t64 = blk & 31, bh = blk >> 5;
    int b = bh >> 3, h = bh & 7;
    int t = threadIdx.x;               // t = l*4 + r
    int l = t >> 2, r = t & 3, q = l >> 4, cl = l & 15;
#pragma unroll
    for (int w = 0; w < 4; w++) {
        int ic = t64 * 4 + w;
        size_t c0 = ((size_t)(bh * 128 + ic)) * 4;
        float o0 = 0.f, o1 = 0.f, o2 = 0.f, o3 = 0.f, lsum = 0.f;
#pragma unroll
        for (int js = 0; js < 4; js++) {
            ushort4 a = *reinterpret_cast<const ushort4*>(PO + (c0 + js) * 1024 + t * 4);
            o0 += bu2f(a.x); o1 += bu2f(a.y); o2 += bu2f(a.z); o3 += bu2f(a.w);
            lsum += PL[(c0 + js) * 16 + q * 4 + r];
        }
        float inv = 1.0f / lsum;
        size_t gro = (size_t)(b * 2048 + ic * 16 + q * 4 + r) * 512 + h * 64;
        out[gro + 0 * 16 + cl] = o0 * inv + x[gro + 0 * 16 + cl];
        out[gro + 1 * 16 + cl] = o1 * inv + x[gro + 1 * 16 + cl];
        out[gro + 2 * 16 + cl] = o2 * inv + x[gro + 2 * 16 + cl];
        out[gro + 3 * 16 + cl] = o3 * inv + x[gro + 3 * 16 + cl];
    }
}

extern "C" void kernel_launch(void* const* d_in, const int* in_sizes, int n_in,
                              void* d_out, int out_size, void* d_ws, size_t ws_size,
                              hipStream_t stream) {
    const float* x   = (const float*)d_in[0];
    const float* adj = (const float*)d_in[1];
    const float* Wq  = (const float*)d_in[2];
    const float* bq  = (const float*)d_in[3];
    const float* Wk  = (const float*)d_in[4];
    const float* bk  = (const float*)d_in[5];
    const float* Wv  = (const float*)d_in[6];
    const float* bv  = (const float*)d_in[7];
    const float* wg  = (const float*)d_in[8];
    // d_in[9] (b_g) unused: row-constant bias cancels in softmax
    float* out = (float*)d_out;
    char* ws = (char*)d_ws;
    unsigned short* Qs = (unsigned short*)(ws + OFF_QS);
    unsigned short* Kb = (unsigned short*)(ws + OFF_KB);
    unsigned short* Vt = (unsigned short*)(ws + OFF_VT);
    float* cv2 = (float*)(ws + OFF_CV);
    unsigned short* xb = (unsigned short*)(ws + OFF_XB);
    unsigned short* wt = (unsigned short*)(ws + OFF_WT);
    unsigned short* mqp = (unsigned short*)(ws + OFF_MQ);
    unsigned short* PO = (unsigned short*)(ws + OFF_PO);
    float* PL = (float*)(ws + OFF_PL);

    k_prepwt<<<1216, 256, 0, stream>>>(x, wg, Wq, Wk, Wv, xb, cv2, wt);
    k_mid<<<8960, 256, 0, stream>>>(adj, cv2, mqp, xb, wt, bq, bk, bv, Qs, Kb, Vt);
    k_attn<<<1024, 256, 0, stream>>>(Qs, Kb, Vt, mqp, PO, PL);
    k_comb<<<512, 256, 0, stream>>>(PO, PL, x, out);
}